// Round 1
// baseline (5528.411 us; speedup 1.0000x reference)
//
#include <hip/hip_runtime.h>
#include <math.h>

#define Tn 1024
#define Bn 16
#define Sn 512
#define Vn 32
#define Cn 512
#define Dn 512
#define En 512
#define Ln 4
#define Kw 3
#define MROWS (Tn*Bn)   // 16384

// ---------------- small setup kernels ----------------

__global__ void emb_kernel(const int* __restrict__ labels, const float* __restrict__ labW,
                           const float* __restrict__ timeW, float* __restrict__ emb) {
  int idx = blockIdx.x * 256 + threadIdx.x;       // over T*B*D
  int dd = idx & (Dn - 1);
  int m = idx >> 9;                                // t*B+b
  int t = m >> 4;
  emb[idx] = labW[labels[m] * Dn + dd] + timeW[t * Dn + dd];
}

// conv weights (L,C,C,K) -> (L,C,K,C)
__global__ void transposeW_kernel(const float* __restrict__ w, float* __restrict__ wt) {
  int idx = blockIdx.x * 256 + threadIdx.x;       // over L*C*C*K
  int k = idx % Kw;
  int tmp = idx / Kw;
  int c = tmp & (Cn - 1);
  tmp >>= 9;
  int o = tmp & (Cn - 1);
  int l = tmp >> 9;
  wt[(((size_t)l * Cn + o) * Kw + k) * Cn + c] = w[idx];
}

// (V,C) -> (C,V)
__global__ void transposeSmall_kernel(const float* __restrict__ w, float* __restrict__ wt) {
  int idx = blockIdx.x * 256 + threadIdx.x;       // over V*C
  int v = idx >> 9;
  int c = idx & (Cn - 1);
  wt[c * Vn + v] = w[idx];
}

__global__ void esum_kernel(const float* __restrict__ enc, float* __restrict__ Esum) {
  int p = blockIdx.x * 256 + threadIdx.x;         // b*E+e, B*E=8192
  float s = 0.f;
  for (int ss = 0; ss < Sn; ++ss) s += enc[(size_t)ss * Bn * En + p];
  Esum[p] = s;
}

// M[b][e1][e2] = sum_s enc[s,b,e1]*enc[s,b,e2]
__global__ __launch_bounds__(256) void gram_kernel(const float* __restrict__ enc,
                                                   float* __restrict__ M) {
  __shared__ float As[16][68];
  __shared__ float Bs[16][68];
  int b = blockIdx.z;
  int e10 = blockIdx.x * 64, e20 = blockIdx.y * 64;
  int tid = threadIdx.x;
  int lk = tid >> 4;            // 0..15 (k row = s)
  int le = (tid & 15) * 4;      // 0..60
  int tx = tid & 15, ty = tid >> 4;
  float acc[4][4] = {};
  for (int s0 = 0; s0 < Sn; s0 += 16) {
    const float* base = enc + ((size_t)(s0 + lk) * Bn + b) * En;
    *(float4*)&As[lk][le] = *(const float4*)(base + e10 + le);
    *(float4*)&Bs[lk][le] = *(const float4*)(base + e20 + le);
    __syncthreads();
#pragma unroll
    for (int k = 0; k < 16; ++k) {
      float4 a4 = *(const float4*)&As[k][ty * 4];
      float4 b4 = *(const float4*)&Bs[k][tx * 4];
      float av[4] = {a4.x, a4.y, a4.z, a4.w};
      float bv[4] = {b4.x, b4.y, b4.z, b4.w};
#pragma unroll
      for (int i = 0; i < 4; ++i)
#pragma unroll
        for (int j = 0; j < 4; ++j) acc[i][j] += av[i] * bv[j];
    }
    __syncthreads();
  }
#pragma unroll
  for (int i = 0; i < 4; ++i)
#pragma unroll
    for (int j = 0; j < 4; ++j)
      M[((size_t)b * En + e10 + ty * 4 + i) * En + e20 + tx * 4 + j] = acc[i][j];
}

// ---------------- generic flat GEMM: C[m,n] (16384x512) = A(16384x512) @ W(512x512)^T ----------------
// EPI: 0: +bias1 | 1: +bias1+bias2 | 2: accumulate into C | 3: +bias1+add[m,n] | 4: C += acc+bias1
template <int EPI>
__global__ __launch_bounds__(256) void gemm512(const float* __restrict__ A,
                                               const float* __restrict__ W,
                                               float* __restrict__ Cmat,
                                               const float* __restrict__ bias1,
                                               const float* __restrict__ bias2,
                                               const float* __restrict__ add) {
  __shared__ float As[16][68];
  __shared__ float Ws[16][68];
  const int tid = threadIdx.x;
  const int m0 = blockIdx.x * 64, n0 = blockIdx.y * 64;
  const int lm = tid >> 2, lk = (tid & 3) * 4;
  const int tx = tid & 15, ty = tid >> 4;
  float acc[4][4] = {};
  const float* ap = A + (size_t)(m0 + lm) * 512 + lk;
  const float* wp = W + (size_t)(n0 + lm) * 512 + lk;
  for (int k0 = 0; k0 < 512; k0 += 16) {
    float4 av = *(const float4*)(ap + k0);
    float4 wv = *(const float4*)(wp + k0);
    As[lk + 0][lm] = av.x; As[lk + 1][lm] = av.y; As[lk + 2][lm] = av.z; As[lk + 3][lm] = av.w;
    Ws[lk + 0][lm] = wv.x; Ws[lk + 1][lm] = wv.y; Ws[lk + 2][lm] = wv.z; Ws[lk + 3][lm] = wv.w;
    __syncthreads();
#pragma unroll
    for (int k = 0; k < 16; ++k) {
      float4 a4 = *(const float4*)&As[k][ty * 4];
      float4 b4 = *(const float4*)&Ws[k][tx * 4];
      float avv[4] = {a4.x, a4.y, a4.z, a4.w};
      float bvv[4] = {b4.x, b4.y, b4.z, b4.w};
#pragma unroll
      for (int i = 0; i < 4; ++i)
#pragma unroll
        for (int j = 0; j < 4; ++j) acc[i][j] += avv[i] * bvv[j];
    }
    __syncthreads();
  }
#pragma unroll
  for (int i = 0; i < 4; ++i) {
    int m = m0 + ty * 4 + i;
#pragma unroll
    for (int j = 0; j < 4; ++j) {
      int n = n0 + tx * 4 + j;
      size_t o = (size_t)m * 512 + n;
      float v = acc[i][j];
      if constexpr (EPI == 0) v += bias1[n];
      else if constexpr (EPI == 1) v += bias1[n] + bias2[n];
      else if constexpr (EPI == 2) v += Cmat[o];
      else if constexpr (EPI == 3) v += bias1[n] + add[o];
      else if constexpr (EPI == 4) v += bias1[n] + Cmat[o];
      Cmat[o] = v;
    }
  }
}

// ---------------- fused causal-conv GLU: conv_out = x*sigmoid(g) + conv_out ----------------
// A' has K'=3*512 columns; column kk = tap*512 + c reads h[(t+tap-2)*B+b, c] (0 if t+tap-2<0)
__global__ __launch_bounds__(256) void glu_conv_kernel(const float* __restrict__ h,
                                                       const float* __restrict__ wtx,
                                                       const float* __restrict__ wtg,
                                                       const float* __restrict__ bx,
                                                       const float* __restrict__ bg,
                                                       float* __restrict__ conv_out) {
  __shared__ float As[16][68];
  __shared__ float WsX[16][68];
  __shared__ float WsG[16][68];
  const int tid = threadIdx.x;
  const int m0 = blockIdx.x * 64, n0 = blockIdx.y * 64;
  const int lm = tid >> 2, lk = (tid & 3) * 4;
  const int tx = tid & 15, ty = tid >> 4;
  float accX[4][4] = {};
  float accG[4][4] = {};
  for (int k0 = 0; k0 < Kw * Cn; k0 += 16) {
    int tap = k0 >> 9;                 // constant within the chunk (512 % 16 == 0)
    int c0 = (k0 & 511) + lk;
    int srow = m0 + lm + (tap - 2) * Bn;
    float4 av = make_float4(0.f, 0.f, 0.f, 0.f);
    if (srow >= 0) av = *(const float4*)(h + (size_t)srow * Cn + c0);
    float4 xv = *(const float4*)(wtx + (size_t)(n0 + lm) * (Kw * Cn) + k0 + lk);
    float4 gv = *(const float4*)(wtg + (size_t)(n0 + lm) * (Kw * Cn) + k0 + lk);
    As[lk + 0][lm] = av.x; As[lk + 1][lm] = av.y; As[lk + 2][lm] = av.z; As[lk + 3][lm] = av.w;
    WsX[lk + 0][lm] = xv.x; WsX[lk + 1][lm] = xv.y; WsX[lk + 2][lm] = xv.z; WsX[lk + 3][lm] = xv.w;
    WsG[lk + 0][lm] = gv.x; WsG[lk + 1][lm] = gv.y; WsG[lk + 2][lm] = gv.z; WsG[lk + 3][lm] = gv.w;
    __syncthreads();
#pragma unroll
    for (int k = 0; k < 16; ++k) {
      float4 a4 = *(const float4*)&As[k][ty * 4];
      float4 x4 = *(const float4*)&WsX[k][tx * 4];
      float4 g4 = *(const float4*)&WsG[k][tx * 4];
      float avv[4] = {a4.x, a4.y, a4.z, a4.w};
      float xvv[4] = {x4.x, x4.y, x4.z, x4.w};
      float gvv[4] = {g4.x, g4.y, g4.z, g4.w};
#pragma unroll
      for (int i = 0; i < 4; ++i)
#pragma unroll
        for (int j = 0; j < 4; ++j) {
          accX[i][j] += avv[i] * xvv[j];
          accG[i][j] += avv[i] * gvv[j];
        }
    }
    __syncthreads();
  }
#pragma unroll
  for (int i = 0; i < 4; ++i) {
    int m = m0 + ty * 4 + i;
#pragma unroll
    for (int j = 0; j < 4; ++j) {
      int n = n0 + tx * 4 + j;
      size_t o = (size_t)m * Cn + n;
      float xval = accX[i][j] + bx[n];
      float gval = accG[i][j] + bg[n];
      float sg = 1.f / (1.f + expf(-gval));
      conv_out[o] = xval * sg + conv_out[o];
    }
  }
}

// ---------------- attention via Gram: ctx[t,b,:] = (d[t,b,:] @ M[b]) / den[t,b] ----------------
__global__ void den_kernel(const float* __restrict__ d, const float* __restrict__ Esum,
                           float* __restrict__ den) {
  int gtid = blockIdx.x * 256 + threadIdx.x;
  int row = gtid >> 6;                 // (t*B+b)
  int lane = threadIdx.x & 63;
  int b = row & (Bn - 1);
  const float* dp = d + (size_t)row * En;
  const float* ep = Esum + b * En;
  float s = 0.f;
  for (int e = lane; e < En; e += 64) s += dp[e] * ep[e];
  for (int off = 32; off; off >>= 1) s += __shfl_down(s, off, 64);
  if (lane == 0) den[row] = s;
}

__global__ __launch_bounds__(256) void ctx_kernel(const float* __restrict__ d,
                                                  const float* __restrict__ M,
                                                  const float* __restrict__ den,
                                                  float* __restrict__ ctx) {
  __shared__ float As[16][68];
  __shared__ float Ws[16][68];
  const int b = blockIdx.z;
  const int t0 = blockIdx.x * 64, n0 = blockIdx.y * 64;
  const int tid = threadIdx.x;
  const int lm = tid >> 2, lk = (tid & 3) * 4;
  const int tx = tid & 15, ty = tid >> 4;
  float acc[4][4] = {};
  const float* ap = d + ((size_t)(t0 + lm) * Bn + b) * En + lk;
  const float* wp = M + ((size_t)b * En + n0 + lm) * En + lk;
  for (int k0 = 0; k0 < 512; k0 += 16) {
    float4 av = *(const float4*)(ap + k0);
    float4 wv = *(const float4*)(wp + k0);
    As[lk + 0][lm] = av.x; As[lk + 1][lm] = av.y; As[lk + 2][lm] = av.z; As[lk + 3][lm] = av.w;
    Ws[lk + 0][lm] = wv.x; Ws[lk + 1][lm] = wv.y; Ws[lk + 2][lm] = wv.z; Ws[lk + 3][lm] = wv.w;
    __syncthreads();
#pragma unroll
    for (int k = 0; k < 16; ++k) {
      float4 a4 = *(const float4*)&As[k][ty * 4];
      float4 b4 = *(const float4*)&Ws[k][tx * 4];
      float avv[4] = {a4.x, a4.y, a4.z, a4.w};
      float bvv[4] = {b4.x, b4.y, b4.z, b4.w};
#pragma unroll
      for (int i = 0; i < 4; ++i)
#pragma unroll
        for (int j = 0; j < 4; ++j) acc[i][j] += avv[i] * bvv[j];
    }
    __syncthreads();
  }
#pragma unroll
  for (int i = 0; i < 4; ++i) {
    int t = t0 + ty * 4 + i;
    int row = t * Bn + b;
    float inv = 1.f / den[row];
#pragma unroll
    for (int j = 0; j < 4; ++j) {
      int n = n0 + tx * 4 + j;
      ctx[(size_t)row * En + n] = acc[i][j] * inv;
    }
  }
}

// ---------------- output projection: out = h@opW^T + emb@orW^T + biases ----------------
// opwT/orwT are (C,V) transposed for coalesced reads
__global__ __launch_bounds__(256) void out_kernel(const float* __restrict__ h,
                                                  const float* __restrict__ emb,
                                                  const float* __restrict__ opwT,
                                                  const float* __restrict__ opb,
                                                  const float* __restrict__ orwT,
                                                  const float* __restrict__ orb,
                                                  float* __restrict__ out) {
  __shared__ float rows[8][1024];
  int m0 = blockIdx.x * 8;
  int tid = threadIdx.x;
  for (int i = tid; i < 8 * 512; i += 256) {
    int r = i >> 9, c = i & 511;
    rows[r][c] = h[(size_t)(m0 + r) * Cn + c];
    rows[r][512 + c] = emb[(size_t)(m0 + r) * Dn + c];
  }
  __syncthreads();
  int r = tid >> 5, v = tid & 31;
  float acc = opb[v] + orb[v];
  for (int c = 0; c < 512; ++c) acc += rows[r][c] * opwT[c * Vn + v];
  for (int c = 0; c < 512; ++c) acc += rows[r][512 + c] * orwT[c * Vn + v];
  out[(size_t)(m0 + r) * Vn + v] = acc;
}

// ---------------- host ----------------

extern "C" void kernel_launch(void* const* d_in, const int* in_sizes, int n_in,
                              void* d_out, int out_size, void* d_ws, size_t ws_size,
                              hipStream_t stream) {
  const int* labels = (const int*)d_in[0];
  const float* enc = (const float*)d_in[1];
  const float* labW = (const float*)d_in[2];
  const float* timeW = (const float*)d_in[3];
  const float* conv_glu_w = (const float*)d_in[4];
  const float* conv_glu_b = (const float*)d_in[5];
  const float* conv_id_w = (const float*)d_in[6];
  const float* conv_id_b = (const float*)d_in[7];
  const float* res_proj_w = (const float*)d_in[8];
  const float* res_proj_b = (const float*)d_in[9];
  const float* inres_w = (const float*)d_in[10];
  const float* inres_b = (const float*)d_in[11];
  const float* in2enc_w = (const float*)d_in[12];
  const float* in2enc_b = (const float*)d_in[13];
  const float* lab2enc_w = (const float*)d_in[14];
  const float* lab2enc_b = (const float*)d_in[15];
  const float* enc2in_w = (const float*)d_in[16];
  const float* enc2in_b = (const float*)d_in[17];
  const float* out_res_w = (const float*)d_in[18];
  const float* out_res_b = (const float*)d_in[19];
  const float* out_proj_w = (const float*)d_in[20];
  const float* out_proj_b = (const float*)d_in[21];
  float* out = (float*)d_out;

  float* ws = (float*)d_ws;
  const size_t BIG = (size_t)MROWS * 512;          // 8,388,608 floats
  float* emb = ws;                                 // BIG
  float* bufA = ws + BIG;                          // BIG
  float* bufB = ws + 2 * BIG;                      // BIG
  float* conv_out = ws + 3 * BIG;                  // BIG
  float* ctxb = ws + 4 * BIG;                      // BIG
  float* Mb = ws + 5 * BIG;                        // B*E*E = 4,194,304
  float* wtg = Mb + (size_t)Bn * En * En;          // 3,145,728
  float* wti = wtg + (size_t)Ln * Cn * Cn * Kw;    // 3,145,728
  float* EsumB = wti + (size_t)Ln * Cn * Cn * Kw;  // 8192
  float* denB = EsumB + Bn * En;                   // 16384
  float* opwT = denB + MROWS;                      // 16384
  float* orwT = opwT + Cn * Vn;                    // 16384

  // setup
  emb_kernel<<<MROWS * Dn / 256, 256, 0, stream>>>(labels, labW, timeW, emb);
  transposeW_kernel<<<Ln * Cn * Cn * Kw / 256, 256, 0, stream>>>(conv_glu_w, wtg);
  transposeW_kernel<<<Ln * Cn * Cn * Kw / 256, 256, 0, stream>>>(conv_id_w, wti);
  transposeSmall_kernel<<<Vn * Cn / 256, 256, 0, stream>>>(out_proj_w, opwT);
  transposeSmall_kernel<<<Vn * Cn / 256, 256, 0, stream>>>(out_res_w, orwT);
  esum_kernel<<<Bn * En / 256, 256, 0, stream>>>(enc, EsumB);
  gram_kernel<<<dim3(En / 64, En / 64, Bn), 256, 0, stream>>>(enc, Mb);

  dim3 ggrid(MROWS / 64, 512 / 64);
  const float* h_in = emb;
  float* dbuf = bufB;
  float* other = bufA;
  for (int l = 0; l < Ln; ++l) {
    // conv_out = h@res_proj^T + res_b
    gemm512<0><<<ggrid, 256, 0, stream>>>(h_in, res_proj_w + (size_t)l * Cn * Cn, conv_out,
                                          res_proj_b + l * Cn, nullptr, nullptr);
    // conv_out += x * sigmoid(g)
    glu_conv_kernel<<<ggrid, 256, 0, stream>>>(h_in, wtg + (size_t)l * Cn * Cn * Kw,
                                               wti + (size_t)l * Cn * Cn * Kw,
                                               conv_glu_b + l * Cn, conv_id_b + l * Cn, conv_out);
    // d = emb@lab2enc^T + lab2enc_b + in2enc_b
    gemm512<1><<<ggrid, 256, 0, stream>>>(emb, lab2enc_w + (size_t)l * En * Dn, dbuf,
                                          lab2enc_b + l * En, in2enc_b + l * En, nullptr);
    // d += conv_out@in2enc^T
    gemm512<2><<<ggrid, 256, 0, stream>>>(conv_out, in2enc_w + (size_t)l * En * Cn, dbuf,
                                          nullptr, nullptr, nullptr);
    // den[t,b] = d . Esum[b]
    den_kernel<<<MROWS * 64 / 256, 256, 0, stream>>>(dbuf, EsumB, denB);
    // ctx = (d @ M[b]) / den
    ctx_kernel<<<dim3(Tn / 64, En / 64, Bn), 256, 0, stream>>>(dbuf, Mb, denB, ctxb);
    // h_out = emb@inres^T + inres_b + conv_out   (reuses d buffer)
    float* h_out = dbuf;
    gemm512<3><<<ggrid, 256, 0, stream>>>(emb, inres_w + (size_t)l * Cn * Dn, h_out,
                                          inres_b + l * Cn, nullptr, conv_out);
    // h_out += ctx@enc2in^T + enc2in_b
    gemm512<4><<<ggrid, 256, 0, stream>>>(ctxb, enc2in_w + (size_t)l * Cn * En, h_out,
                                          enc2in_b + l * Cn, nullptr, nullptr);
    h_in = h_out;
    dbuf = (h_out == bufB) ? bufA : bufB;
  }

  out_kernel<<<MROWS / 8, 256, 0, stream>>>(h_in, emb, opwT, out_proj_b, orwT, out_res_b, out);
}

// Round 2
// 1008.369 us; speedup vs baseline: 5.4825x; 5.4825x over previous
//
#include <hip/hip_runtime.h>
#include <math.h>

#define Tn 1024
#define Bn 16
#define Sn 512
#define Vn 32
#define Cn 512
#define En 512
#define Ln 4
#define Kw 3
#define MROWS 16384
#define PADROWS 32
#define PADE (PADROWS * Cn)

typedef short bf16x8 __attribute__((ext_vector_type(8)));
typedef float f32x4 __attribute__((ext_vector_type(4)));

__device__ __forceinline__ unsigned short cvt_bf16(float x) {
  unsigned u = __builtin_bit_cast(unsigned, x);
  u = (u + 0x7FFFu + ((u >> 16) & 1u)) >> 16;
  return (unsigned short)u;
}
__device__ __forceinline__ float bf2f(unsigned short h) {
  unsigned u = ((unsigned)h) << 16;
  return __builtin_bit_cast(float, u);
}

#define GL16(g, l)                                                                  \
  __builtin_amdgcn_global_load_lds((const __attribute__((address_space(1))) void*)(g), \
                                   (__attribute__((address_space(3))) void*)(l), 16, 0, 0)

// stage a 128x32 bf16 tile (row-major, ld elements) into LDS; 256 threads x 2 x 16B
#define STAGE2(SRC, LD, DST)                                             \
  do {                                                                   \
    {                                                                    \
      int ofs_ = tid * 16;                                               \
      int row_ = ofs_ >> 6, colb_ = ofs_ & 63;                           \
      GL16((SRC) + (size_t)row_ * (LD) + (colb_ >> 1), (char*)(DST) + ofs_); \
    }                                                                    \
    {                                                                    \
      int ofs_ = tid * 16 + 4096;                                        \
      int row_ = ofs_ >> 6, colb_ = ofs_ & 63;                           \
      GL16((SRC) + (size_t)row_ * (LD) + (colb_ >> 1), (char*)(DST) + ofs_); \
    }                                                                    \
  } while (0)

__device__ __forceinline__ void mf_frags(const unsigned short* As, const unsigned short* Bs,
                                         int lane, int waveM, int waveN, f32x4 acc[4][4]) {
  const char* ab = (const char*)As;
  const char* bb = (const char*)Bs;
  int ao = (waveM + (lane & 15)) * 64 + (lane >> 4) * 16;
  int bo = (waveN + (lane & 15)) * 64 + (lane >> 4) * 16;
  bf16x8 af[4], bfv[4];
#pragma unroll
  for (int i = 0; i < 4; ++i) af[i] = *(const bf16x8*)(ab + ao + i * 1024);
#pragma unroll
  for (int j = 0; j < 4; ++j) bfv[j] = *(const bf16x8*)(bb + bo + j * 1024);
#pragma unroll
  for (int i = 0; i < 4; ++i)
#pragma unroll
    for (int j = 0; j < 4; ++j)
      acc[i][j] = __builtin_amdgcn_mfma_f32_16x16x32_bf16(af[i], bfv[j], acc[i][j], 0, 0, 0);
}

// dual-B (x and g) with shared A
__device__ __forceinline__ void mf_frags2(const unsigned short* As, const unsigned short* Xs,
                                          const unsigned short* Gs, int lane, int waveM, int waveN,
                                          f32x4 aX[4][4], f32x4 aG[4][4]) {
  const char* ab = (const char*)As;
  const char* xb = (const char*)Xs;
  const char* gb = (const char*)Gs;
  int ao = (waveM + (lane & 15)) * 64 + (lane >> 4) * 16;
  int bo = (waveN + (lane & 15)) * 64 + (lane >> 4) * 16;
  bf16x8 af[4], xf[4], gf[4];
#pragma unroll
  for (int i = 0; i < 4; ++i) af[i] = *(const bf16x8*)(ab + ao + i * 1024);
#pragma unroll
  for (int j = 0; j < 4; ++j) xf[j] = *(const bf16x8*)(xb + bo + j * 1024);
#pragma unroll
  for (int j = 0; j < 4; ++j) gf[j] = *(const bf16x8*)(gb + bo + j * 1024);
#pragma unroll
  for (int i = 0; i < 4; ++i)
#pragma unroll
    for (int j = 0; j < 4; ++j) {
      aX[i][j] = __builtin_amdgcn_mfma_f32_16x16x32_bf16(af[i], xf[j], aX[i][j], 0, 0, 0);
      aG[i][j] = __builtin_amdgcn_mfma_f32_16x16x32_bf16(af[i], gf[j], aG[i][j], 0, 0, 0);
    }
}

// ---------------- setup kernels ----------------

__global__ __launch_bounds__(256) void emb_kernel(const int* __restrict__ labels,
                                                  const float* __restrict__ labW,
                                                  const float* __restrict__ timeW,
                                                  unsigned short* __restrict__ embd) {
  int idx = blockIdx.x * 256 + threadIdx.x;  // over T*B*D
  int dd = idx & 511;
  int m = idx >> 9;
  int t = m >> 4;
  embd[idx] = cvt_bf16(labW[labels[m] * 512 + dd] + timeW[t * 512 + dd]);
}

__global__ void k_zeropad(unsigned short* a, unsigned short* b, unsigned short* c) {
  int i = blockIdx.x * 256 + threadIdx.x;  // 16384
  a[i] = 0; b[i] = 0; c[i] = 0;
}

// conv weights (L,C,C,K) fp32 -> (L,C,K*C) bf16
__global__ void transposeW_kernel(const float* __restrict__ w, unsigned short* __restrict__ wt) {
  int idx = blockIdx.x * 256 + threadIdx.x;  // over L*C*C*K
  int k = idx % Kw;
  int tmp = idx / Kw;
  int c = tmp & 511;
  tmp >>= 9;
  int o = tmp & 511;
  int l = tmp >> 9;
  wt[(((size_t)l * Cn + o) * Kw + k) * Cn + c] = cvt_bf16(w[idx]);
}

__global__ void cast_kernel(const float* __restrict__ src, unsigned short* __restrict__ dst, int n) {
  int i = blockIdx.x * 256 + threadIdx.x;
  if (i < n) dst[i] = cvt_bf16(src[i]);
}

// (V,C) -> (C,V) fp32
__global__ void transposeSmall_kernel(const float* __restrict__ w, float* __restrict__ wt) {
  int idx = blockIdx.x * 256 + threadIdx.x;  // over V*C
  int v = idx >> 9;
  int c = idx & 511;
  wt[c * Vn + v] = w[idx];
}

__global__ void esum_kernel(const float* __restrict__ enc, float* __restrict__ Esum) {
  int p = blockIdx.x * 256 + threadIdx.x;  // b*E+e
  float s = 0.f;
  for (int ss = 0; ss < Sn; ++ss) s += enc[(size_t)ss * Bn * En + p];
  Esum[p] = s;
}

// enc (S,B,E) fp32 -> encT (B,E,S) bf16
__global__ __launch_bounds__(256) void k_encT(const float* __restrict__ enc,
                                              unsigned short* __restrict__ encT) {
  __shared__ unsigned short t[64][66];
  int s0 = blockIdx.x * 64, e0 = blockIdx.y * 64, b = blockIdx.z;
  int c = threadIdx.x & 63, r0 = threadIdx.x >> 6;
#pragma unroll
  for (int i = 0; i < 16; ++i) {
    int r = r0 + i * 4;
    t[r][c] = cvt_bf16(enc[((size_t)(s0 + r) * Bn + b) * En + e0 + c]);
  }
  __syncthreads();
#pragma unroll
  for (int i = 0; i < 16; ++i) {
    int r = r0 + i * 4;
    encT[((size_t)b * En + e0 + r) * Sn + s0 + c] = t[c][r];
  }
}

// ---------------- MFMA GEMM kernels ----------------

// conv_out = h @ res_w^T + bias   (fp32 out)
__global__ __launch_bounds__(256) void k_res(const unsigned short* __restrict__ hd,
                                             const unsigned short* __restrict__ W,
                                             const float* __restrict__ bias,
                                             float* __restrict__ outC) {
  __shared__ unsigned short lsA[2][4096], lsB[2][4096];
  const int tid = threadIdx.x;
  const int lane = tid & 63, wave = tid >> 6;
  const int waveM = (wave >> 1) * 64, waveN = (wave & 1) * 64;
  const int m0 = blockIdx.x * 128, n0 = blockIdx.y * 128;
  f32x4 acc[4][4] = {};
  const unsigned short* A0 = hd + (size_t)m0 * 512;
  const unsigned short* W0 = W + (size_t)n0 * 512;
  STAGE2(A0, 512, lsA[0]);
  STAGE2(W0, 512, lsB[0]);
  __syncthreads();
  int buf = 0;
  for (int s = 0; s < 16; ++s) {
    if (s < 15) {
      STAGE2(A0 + (s + 1) * 32, 512, lsA[buf ^ 1]);
      STAGE2(W0 + (s + 1) * 32, 512, lsB[buf ^ 1]);
    }
    mf_frags(lsA[buf], lsB[buf], lane, waveM, waveN, acc);
    __syncthreads();
    buf ^= 1;
  }
#pragma unroll
  for (int i = 0; i < 4; ++i)
#pragma unroll
    for (int j = 0; j < 4; ++j) {
      int col = n0 + waveN + j * 16 + (lane & 15);
      float bj = bias[col];
#pragma unroll
      for (int r = 0; r < 4; ++r) {
        int row = m0 + waveM + i * 16 + (lane >> 4) * 4 + r;
        outC[(size_t)row * 512 + col] = acc[i][j][r] + bj;
      }
    }
}

// conv_out = x*sigmoid(g) + conv_out ; also bf16 copy
__global__ __launch_bounds__(256) void k_glu(const unsigned short* __restrict__ hd,
                                             const unsigned short* __restrict__ Wx,
                                             const unsigned short* __restrict__ Wg,
                                             const float* __restrict__ bx,
                                             const float* __restrict__ bg,
                                             float* __restrict__ conv,
                                             unsigned short* __restrict__ convbf) {
  __shared__ unsigned short lsA[2][4096], lsX[2][4096], lsG[2][4096];
  const int tid = threadIdx.x;
  const int lane = tid & 63, wave = tid >> 6;
  const int waveM = (wave >> 1) * 64, waveN = (wave & 1) * 64;
  const int m0 = blockIdx.x * 128, n0 = blockIdx.y * 128;
  f32x4 aX[4][4] = {}, aG[4][4] = {};
  const unsigned short* Wx0 = Wx + (size_t)n0 * 1536;
  const unsigned short* Wg0 = Wg + (size_t)n0 * 1536;
  // stage step s: tap = s>>4, kk = (s&15)*32 ; A row shift = (tap-2)*16 (pad rows guarantee >=0)
  {
    const unsigned short* As = hd + ((ptrdiff_t)m0 - 2 * Bn) * 512;
    STAGE2(As, 512, lsA[0]);
    STAGE2(Wx0, 1536, lsX[0]);
    STAGE2(Wg0, 1536, lsG[0]);
  }
  __syncthreads();
  int buf = 0;
  for (int s = 0; s < 48; ++s) {
    if (s < 47) {
      int sn = s + 1;
      int tap = sn >> 4, kk = (sn & 15) * 32;
      const unsigned short* As = hd + ((ptrdiff_t)m0 + (tap - 2) * Bn) * 512 + kk;
      STAGE2(As, 512, lsA[buf ^ 1]);
      STAGE2(Wx0 + sn * 32, 1536, lsX[buf ^ 1]);
      STAGE2(Wg0 + sn * 32, 1536, lsG[buf ^ 1]);
    }
    mf_frags2(lsA[buf], lsX[buf], lsG[buf], lane, waveM, waveN, aX, aG);
    __syncthreads();
    buf ^= 1;
  }
#pragma unroll
  for (int i = 0; i < 4; ++i)
#pragma unroll
    for (int j = 0; j < 4; ++j) {
      int col = n0 + waveN + j * 16 + (lane & 15);
      float bxv = bx[col], bgv = bg[col];
#pragma unroll
      for (int r = 0; r < 4; ++r) {
        int row = m0 + waveM + i * 16 + (lane >> 4) * 4 + r;
        size_t o = (size_t)row * 512 + col;
        float xv = aX[i][j][r] + bxv;
        float gv = aG[i][j][r] + bgv;
        float sg = 1.f / (1.f + __expf(-gv));
        float res = xv * sg + conv[o];
        conv[o] = res;
        convbf[o] = cvt_bf16(res);
      }
    }
}

// dual-source GEMM, K=1024.  EPI 0: d = acc+b1+b2 -> bf16.  EPI 1: h = acc+b1+b2+addf -> bf16
template <int EPI>
__global__ __launch_bounds__(256) void k_dual(const unsigned short* __restrict__ A1,
                                              const unsigned short* __restrict__ A2,
                                              const unsigned short* __restrict__ W1,
                                              const unsigned short* __restrict__ W2,
                                              const float* __restrict__ b1,
                                              const float* __restrict__ b2,
                                              const float* __restrict__ addf,
                                              unsigned short* __restrict__ outbf) {
  __shared__ unsigned short lsA[2][4096], lsB[2][4096];
  const int tid = threadIdx.x;
  const int lane = tid & 63, wave = tid >> 6;
  const int waveM = (wave >> 1) * 64, waveN = (wave & 1) * 64;
  const int m0 = blockIdx.x * 128, n0 = blockIdx.y * 128;
  f32x4 acc[4][4] = {};
  const unsigned short* A1m = A1 + (size_t)m0 * 512;
  const unsigned short* A2m = A2 + (size_t)m0 * 512;
  const unsigned short* W1n = W1 + (size_t)n0 * 512;
  const unsigned short* W2n = W2 + (size_t)n0 * 512;
  STAGE2(A1m, 512, lsA[0]);
  STAGE2(W1n, 512, lsB[0]);
  __syncthreads();
  int buf = 0;
  for (int s = 0; s < 32; ++s) {
    if (s < 31) {
      int sn = s + 1;
      const unsigned short* As = (sn < 16) ? A1m + sn * 32 : A2m + (sn - 16) * 32;
      const unsigned short* Ws = (sn < 16) ? W1n + sn * 32 : W2n + (sn - 16) * 32;
      STAGE2(As, 512, lsA[buf ^ 1]);
      STAGE2(Ws, 512, lsB[buf ^ 1]);
    }
    mf_frags(lsA[buf], lsB[buf], lane, waveM, waveN, acc);
    __syncthreads();
    buf ^= 1;
  }
#pragma unroll
  for (int i = 0; i < 4; ++i)
#pragma unroll
    for (int j = 0; j < 4; ++j) {
      int col = n0 + waveN + j * 16 + (lane & 15);
      float bb = b1[col] + b2[col];
#pragma unroll
      for (int r = 0; r < 4; ++r) {
        int row = m0 + waveM + i * 16 + (lane >> 4) * 4 + r;
        size_t o = (size_t)row * 512 + col;
        float v = acc[i][j][r] + bb;
        if constexpr (EPI == 1) v += addf[o];
        outbf[o] = cvt_bf16(v);
      }
    }
}

// Gram: M[b] = encT[b] @ encT[b]^T  (E x E, bf16 out)
__global__ __launch_bounds__(256) void k_gram(const unsigned short* __restrict__ encT,
                                              unsigned short* __restrict__ Mbf) {
  __shared__ unsigned short lsA[2][4096], lsB[2][4096];
  const int tid = threadIdx.x;
  const int lane = tid & 63, wave = tid >> 6;
  const int waveM = (wave >> 1) * 64, waveN = (wave & 1) * 64;
  const int b = blockIdx.z;
  const int e10 = blockIdx.x * 128, e20 = blockIdx.y * 128;
  f32x4 acc[4][4] = {};
  const unsigned short* A0 = encT + ((size_t)b * En + e10) * Sn;
  const unsigned short* W0 = encT + ((size_t)b * En + e20) * Sn;
  STAGE2(A0, 512, lsA[0]);
  STAGE2(W0, 512, lsB[0]);
  __syncthreads();
  int buf = 0;
  for (int s = 0; s < 16; ++s) {
    if (s < 15) {
      STAGE2(A0 + (s + 1) * 32, 512, lsA[buf ^ 1]);
      STAGE2(W0 + (s + 1) * 32, 512, lsB[buf ^ 1]);
    }
    mf_frags(lsA[buf], lsB[buf], lane, waveM, waveN, acc);
    __syncthreads();
    buf ^= 1;
  }
#pragma unroll
  for (int i = 0; i < 4; ++i)
#pragma unroll
    for (int j = 0; j < 4; ++j) {
      int col = e20 + waveN + j * 16 + (lane & 15);
#pragma unroll
      for (int r = 0; r < 4; ++r) {
        int row = e10 + waveM + i * 16 + (lane >> 4) * 4 + r;
        Mbf[((size_t)b * En + row) * En + col] = cvt_bf16(acc[i][j][r]);
      }
    }
}

// den[row] = d[row] . Esum[b]
__global__ __launch_bounds__(256) void den_kernel(const unsigned short* __restrict__ d,
                                                  const float* __restrict__ Esum,
                                                  float* __restrict__ den) {
  int gtid = blockIdx.x * 256 + threadIdx.x;
  int row = gtid >> 6;
  int lane = threadIdx.x & 63;
  int b = row & 15;
  const unsigned short* dp = d + (size_t)row * 512 + lane * 8;
  const float* ep = Esum + b * 512 + lane * 8;
  float s = 0.f;
#pragma unroll
  for (int q = 0; q < 8; ++q) s += bf2f(dp[q]) * ep[q];
  for (int off = 32; off; off >>= 1) s += __shfl_down(s, off, 64);
  if (lane == 0) den[row] = s;
}

// ctx = (d @ M[b]) / den  -> bf16
__global__ __launch_bounds__(256) void k_ctx(const unsigned short* __restrict__ dbf,
                                             const unsigned short* __restrict__ Mbf,
                                             const float* __restrict__ den,
                                             unsigned short* __restrict__ ctxbf) {
  __shared__ unsigned short lsA[2][4096], lsB[2][4096];
  const int tid = threadIdx.x;
  const int lane = tid & 63, wave = tid >> 6;
  const int waveM = (wave >> 1) * 64, waveN = (wave & 1) * 64;
  const int b = blockIdx.z;
  const int t0 = blockIdx.x * 128, n0 = blockIdx.y * 128;
  f32x4 acc[4][4] = {};
  const unsigned short* A0 = dbf + ((size_t)t0 * Bn + b) * 512;  // ld = Bn*512
  const unsigned short* W0 = Mbf + ((size_t)b * En + n0) * 512;
  STAGE2(A0, 8192, lsA[0]);
  STAGE2(W0, 512, lsB[0]);
  __syncthreads();
  int buf = 0;
  for (int s = 0; s < 16; ++s) {
    if (s < 15) {
      STAGE2(A0 + (s + 1) * 32, 8192, lsA[buf ^ 1]);
      STAGE2(W0 + (s + 1) * 32, 512, lsB[buf ^ 1]);
    }
    mf_frags(lsA[buf], lsB[buf], lane, waveM, waveN, acc);
    __syncthreads();
    buf ^= 1;
  }
#pragma unroll
  for (int i = 0; i < 4; ++i) {
    float inv[4];
#pragma unroll
    for (int r = 0; r < 4; ++r) {
      int t = t0 + waveM + i * 16 + (lane >> 4) * 4 + r;
      inv[r] = 1.f / den[t * Bn + b];
    }
#pragma unroll
    for (int j = 0; j < 4; ++j) {
      int col = n0 + waveN + j * 16 + (lane & 15);
#pragma unroll
      for (int r = 0; r < 4; ++r) {
        int t = t0 + waveM + i * 16 + (lane >> 4) * 4 + r;
        ctxbf[((size_t)t * Bn + b) * 512 + col] = cvt_bf16(acc[i][j][r] * inv[r]);
      }
    }
  }
}

// out = h@opW^T + emb@orW^T + biases (fp32)
__global__ __launch_bounds__(256) void out_kernel(const unsigned short* __restrict__ hd,
                                                  const unsigned short* __restrict__ embd,
                                                  const float* __restrict__ opwT,
                                                  const float* __restrict__ opb,
                                                  const float* __restrict__ orwT,
                                                  const float* __restrict__ orb,
                                                  float* __restrict__ out) {
  __shared__ float rows[8][1024];
  int m0 = blockIdx.x * 8;
  int tid = threadIdx.x;
  for (int i = tid; i < 8 * 512; i += 256) {
    int r = i >> 9, c = i & 511;
    rows[r][c] = bf2f(hd[(size_t)(m0 + r) * 512 + c]);
    rows[r][512 + c] = bf2f(embd[(size_t)(m0 + r) * 512 + c]);
  }
  __syncthreads();
  int r = tid >> 5, v = tid & 31;
  float acc = opb[v] + orb[v];
  for (int c = 0; c < 512; ++c) acc += rows[r][c] * opwT[c * Vn + v];
  for (int c = 0; c < 512; ++c) acc += rows[r][512 + c] * orwT[c * Vn + v];
  out[(size_t)(m0 + r) * Vn + v] = acc;
}

// ---------------- host ----------------

extern "C" void kernel_launch(void* const* d_in, const int* in_sizes, int n_in,
                              void* d_out, int out_size, void* d_ws, size_t ws_size,
                              hipStream_t stream) {
  const int* labels = (const int*)d_in[0];
  const float* enc = (const float*)d_in[1];
  const float* labW = (const float*)d_in[2];
  const float* timeW = (const float*)d_in[3];
  const float* conv_glu_w = (const float*)d_in[4];
  const float* conv_glu_b = (const float*)d_in[5];
  const float* conv_id_w = (const float*)d_in[6];
  const float* conv_id_b = (const float*)d_in[7];
  const float* res_proj_w = (const float*)d_in[8];
  const float* res_proj_b = (const float*)d_in[9];
  const float* inres_w = (const float*)d_in[10];
  const float* inres_b = (const float*)d_in[11];
  const float* in2enc_w = (const float*)d_in[12];
  const float* in2enc_b = (const float*)d_in[13];
  const float* lab2enc_w = (const float*)d_in[14];
  const float* lab2enc_b = (const float*)d_in[15];
  const float* enc2in_w = (const float*)d_in[16];
  const float* enc2in_b = (const float*)d_in[17];
  const float* out_res_w = (const float*)d_in[18];
  const float* out_res_b = (const float*)d_in[19];
  const float* out_proj_w = (const float*)d_in[20];
  const float* out_proj_b = (const float*)d_in[21];
  float* out = (float*)d_out;

  char* cur = (char*)d_ws;
  auto alloc = [&](size_t bytes) {
    char* p = cur;
    cur += (bytes + 255) & ~(size_t)255;
    return p;
  };
  const size_t BIG = (size_t)MROWS * 512;
  float* conv = (float*)alloc(BIG * 4);
  float* den = (float*)alloc(MROWS * 4);
  float* EsumB = (float*)alloc(Bn * En * 4);
  float* opwT = (float*)alloc(Cn * Vn * 4);
  float* orwT = (float*)alloc(Cn * Vn * 4);
  unsigned short* embp = (unsigned short*)alloc((PADE + BIG) * 2);
  unsigned short* h0p = (unsigned short*)alloc((PADE + BIG) * 2);
  unsigned short* h1p = (unsigned short*)alloc((PADE + BIG) * 2);
  unsigned short* convbf = (unsigned short*)alloc(BIG * 2);
  unsigned short* dbf = (unsigned short*)alloc(BIG * 2);
  unsigned short* ctxbf = (unsigned short*)alloc(BIG * 2);
  unsigned short* encT = (unsigned short*)alloc((size_t)Bn * En * Sn * 2);
  unsigned short* Mbf = (unsigned short*)alloc((size_t)Bn * En * En * 2);
  unsigned short* wres = (unsigned short*)alloc((size_t)Ln * Cn * Cn * 2);
  unsigned short* wgx = (unsigned short*)alloc((size_t)Ln * Cn * Cn * Kw * 2);
  unsigned short* wgg = (unsigned short*)alloc((size_t)Ln * Cn * Cn * Kw * 2);
  unsigned short* w_i2e = (unsigned short*)alloc((size_t)Ln * En * Cn * 2);
  unsigned short* w_l2e = (unsigned short*)alloc((size_t)Ln * En * Cn * 2);
  unsigned short* w_inr = (unsigned short*)alloc((size_t)Ln * Cn * Cn * 2);
  unsigned short* w_e2i = (unsigned short*)alloc((size_t)Ln * Cn * En * 2);

  unsigned short* embd = embp + PADE;
  unsigned short* h0d = h0p + PADE;
  unsigned short* h1d = h1p + PADE;

  const int WN = Ln * Cn * Cn;  // 1,048,576

  // setup
  emb_kernel<<<MROWS * 512 / 256, 256, 0, stream>>>(labels, labW, timeW, embd);
  k_zeropad<<<PADE / 256, 256, 0, stream>>>(embp, h0p, h1p);
  transposeW_kernel<<<WN * Kw / 256, 256, 0, stream>>>(conv_glu_w, wgx);
  transposeW_kernel<<<WN * Kw / 256, 256, 0, stream>>>(conv_id_w, wgg);
  cast_kernel<<<WN / 256, 256, 0, stream>>>(res_proj_w, wres, WN);
  cast_kernel<<<WN / 256, 256, 0, stream>>>(in2enc_w, w_i2e, WN);
  cast_kernel<<<WN / 256, 256, 0, stream>>>(lab2enc_w, w_l2e, WN);
  cast_kernel<<<WN / 256, 256, 0, stream>>>(inres_w, w_inr, WN);
  cast_kernel<<<WN / 256, 256, 0, stream>>>(enc2in_w, w_e2i, WN);
  transposeSmall_kernel<<<Vn * Cn / 256, 256, 0, stream>>>(out_proj_w, opwT);
  transposeSmall_kernel<<<Vn * Cn / 256, 256, 0, stream>>>(out_res_w, orwT);
  esum_kernel<<<Bn * En / 256, 256, 0, stream>>>(enc, EsumB);
  k_encT<<<dim3(Sn / 64, En / 64, Bn), 256, 0, stream>>>(enc, encT);
  k_gram<<<dim3(En / 128, En / 128, Bn), 256, 0, stream>>>(encT, Mbf);

  dim3 ggrid(MROWS / 128, 512 / 128);
  const unsigned short* hdata = embd;
  unsigned short* hbufs[2] = {h0d, h1d};
  for (int l = 0; l < Ln; ++l) {
    const size_t wo = (size_t)l * Cn * Cn;
    const size_t wg = (size_t)l * Cn * Cn * Kw;
    k_res<<<ggrid, 256, 0, stream>>>(hdata, wres + wo, res_proj_b + l * Cn, conv);
    k_glu<<<ggrid, 256, 0, stream>>>(hdata, wgx + wg, wgg + wg, conv_glu_b + l * Cn,
                                     conv_id_b + l * Cn, conv, convbf);
    k_dual<0><<<ggrid, 256, 0, stream>>>(convbf, embd, w_i2e + wo, w_l2e + wo,
                                         in2enc_b + l * En, lab2enc_b + l * En, nullptr, dbf);
    den_kernel<<<MROWS / 4, 256, 0, stream>>>(dbf, EsumB, den);
    k_ctx<<<dim3(Tn / 128, En / 128, Bn), 256, 0, stream>>>(dbf, Mbf, den, ctxbf);
    k_dual<1><<<ggrid, 256, 0, stream>>>(embd, ctxbf, w_inr + wo, w_e2i + wo,
                                         inres_b + l * Cn, enc2in_b + l * Cn, conv, hbufs[l & 1]);
    hdata = hbufs[l & 1];
  }

  out_kernel<<<MROWS / 8, 256, 0, stream>>>(hdata, embd, opwT, out_proj_b, orwT, out_res_b, out);
}

// Round 3
// 927.822 us; speedup vs baseline: 5.9585x; 1.0868x over previous
//
#include <hip/hip_runtime.h>
#include <math.h>

#define Tn 1024
#define Bn 16
#define Sn 512
#define Vn 32
#define Cn 512
#define En 512
#define Ln 4
#define Kw 3
#define MROWS 16384
#define PADROWS 32
#define PADE (PADROWS * Cn)

typedef short bf16x8 __attribute__((ext_vector_type(8)));
typedef float f32x4 __attribute__((ext_vector_type(4)));

__device__ __forceinline__ unsigned short cvt_bf16(float x) {
  unsigned u = __builtin_bit_cast(unsigned, x);
  u = (u + 0x7FFFu + ((u >> 16) & 1u)) >> 16;
  return (unsigned short)u;
}
__device__ __forceinline__ float bf2f(unsigned short h) {
  unsigned u = ((unsigned)h) << 16;
  return __builtin_bit_cast(float, u);
}

#define GL16(g, l)                                                                     \
  __builtin_amdgcn_global_load_lds((const __attribute__((address_space(1))) void*)(g), \
                                   (__attribute__((address_space(3))) void*)(l), 16, 0, 0)

// stage a 128x32 bf16 tile (row-major, ld elements) into LDS; 256 threads x 2 x 16B
#define STAGE2(SRC, LD, DST)                                                 \
  do {                                                                       \
    {                                                                        \
      int ofs_ = tid * 16;                                                   \
      int row_ = ofs_ >> 6, colb_ = ofs_ & 63;                               \
      GL16((SRC) + (size_t)row_ * (LD) + (colb_ >> 1), (char*)(DST) + ofs_); \
    }                                                                        \
    {                                                                        \
      int ofs_ = tid * 16 + 4096;                                            \
      int row_ = ofs_ >> 6, colb_ = ofs_ & 63;                               \
      GL16((SRC) + (size_t)row_ * (LD) + (colb_ >> 1), (char*)(DST) + ofs_); \
    }                                                                        \
  } while (0)

// counted-vmcnt pipeline barriers (T3/T4): previous stage's loads complete,
// current stage's stay in flight across the MFMA phase.
template <int N>
__device__ __forceinline__ void pipe_wait() {
  asm volatile("s_waitcnt vmcnt(%0)\n\ts_barrier" ::"i"(N) : "memory");
}
__device__ __forceinline__ void pipe_tail() {
  asm volatile("s_waitcnt lgkmcnt(0)\n\ts_barrier" ::: "memory");
}

__device__ __forceinline__ void mf_frags(const unsigned short* As, const unsigned short* Bs,
                                         int lane, int waveM, int waveN, f32x4 acc[4][4]) {
  const char* ab = (const char*)As;
  const char* bb = (const char*)Bs;
  int ao = (waveM + (lane & 15)) * 64 + (lane >> 4) * 16;
  int bo = (waveN + (lane & 15)) * 64 + (lane >> 4) * 16;
  bf16x8 af[4], bfv[4];
#pragma unroll
  for (int i = 0; i < 4; ++i) af[i] = *(const bf16x8*)(ab + ao + i * 1024);
#pragma unroll
  for (int j = 0; j < 4; ++j) bfv[j] = *(const bf16x8*)(bb + bo + j * 1024);
#pragma unroll
  for (int i = 0; i < 4; ++i)
#pragma unroll
    for (int j = 0; j < 4; ++j)
      acc[i][j] = __builtin_amdgcn_mfma_f32_16x16x32_bf16(af[i], bfv[j], acc[i][j], 0, 0, 0);
}

__device__ __forceinline__ void mf_frags2(const unsigned short* As, const unsigned short* Xs,
                                          const unsigned short* Gs, int lane, int waveM, int waveN,
                                          f32x4 aX[4][4], f32x4 aG[4][4]) {
  const char* ab = (const char*)As;
  const char* xb = (const char*)Xs;
  const char* gb = (const char*)Gs;
  int ao = (waveM + (lane & 15)) * 64 + (lane >> 4) * 16;
  int bo = (waveN + (lane & 15)) * 64 + (lane >> 4) * 16;
  bf16x8 af[4], xf[4], gf[4];
#pragma unroll
  for (int i = 0; i < 4; ++i) af[i] = *(const bf16x8*)(ab + ao + i * 1024);
#pragma unroll
  for (int j = 0; j < 4; ++j) xf[j] = *(const bf16x8*)(xb + bo + j * 1024);
#pragma unroll
  for (int j = 0; j < 4; ++j) gf[j] = *(const bf16x8*)(gb + bo + j * 1024);
#pragma unroll
  for (int i = 0; i < 4; ++i)
#pragma unroll
    for (int j = 0; j < 4; ++j) {
      aX[i][j] = __builtin_amdgcn_mfma_f32_16x16x32_bf16(af[i], xf[j], aX[i][j], 0, 0, 0);
      aG[i][j] = __builtin_amdgcn_mfma_f32_16x16x32_bf16(af[i], gf[j], aG[i][j], 0, 0, 0);
    }
}

// shared 16-step (K=512) pipelined GEMM inner loop
__device__ __forceinline__ void gemm16_pipe(const unsigned short* A0, int lda,
                                            const unsigned short* W0, int ldw,
                                            unsigned short (*lsA)[4096],
                                            unsigned short (*lsB)[4096], int tid, int lane,
                                            int waveM, int waveN, f32x4 acc[4][4]) {
  STAGE2(A0, lda, lsA[0]);
  STAGE2(W0, ldw, lsB[0]);
  int buf = 0;
  for (int s = 0; s < 16; ++s) {
    if (s < 15) {
      STAGE2(A0 + (s + 1) * 32, lda, lsA[buf ^ 1]);
      STAGE2(W0 + (s + 1) * 32, ldw, lsB[buf ^ 1]);
      pipe_wait<4>();
    } else {
      pipe_wait<0>();
    }
    mf_frags(lsA[buf], lsB[buf], lane, waveM, waveN, acc);
    pipe_tail();
    buf ^= 1;
  }
}

// ---------------- setup kernels ----------------

__global__ __launch_bounds__(256) void emb_kernel(const int* __restrict__ labels,
                                                  const float* __restrict__ labW,
                                                  const float* __restrict__ timeW,
                                                  unsigned short* __restrict__ embd) {
  int idx = blockIdx.x * 256 + threadIdx.x;
  int dd = idx & 511;
  int m = idx >> 9;
  int t = m >> 4;
  embd[idx] = cvt_bf16(labW[labels[m] * 512 + dd] + timeW[t * 512 + dd]);
}

__global__ void k_zeropad(unsigned short* a, unsigned short* b, unsigned short* c) {
  int i = blockIdx.x * 256 + threadIdx.x;
  a[i] = 0; b[i] = 0; c[i] = 0;
}

// conv weights (L,C,C,K) fp32 -> (L,C,K*C) bf16
__global__ void transposeW_kernel(const float* __restrict__ w, unsigned short* __restrict__ wt) {
  int idx = blockIdx.x * 256 + threadIdx.x;
  int k = idx % Kw;
  int tmp = idx / Kw;
  int c = tmp & 511;
  tmp >>= 9;
  int o = tmp & 511;
  int l = tmp >> 9;
  wt[(((size_t)l * Cn + o) * Kw + k) * Cn + c] = cvt_bf16(w[idx]);
}

__global__ void cast_kernel(const float* __restrict__ src, unsigned short* __restrict__ dst,
                            int n) {
  int i = blockIdx.x * 256 + threadIdx.x;
  if (i < n) dst[i] = cvt_bf16(src[i]);
}

// per-layer 512x512 transpose, fp32 -> bf16 (for res_w^T)
__global__ __launch_bounds__(256) void k_tr512(const float* __restrict__ w,
                                               unsigned short* __restrict__ wt) {
  __shared__ unsigned short t[64][65];
  int r0 = blockIdx.x * 64, c0 = blockIdx.y * 64;
  size_t base = (size_t)blockIdx.z * 512 * 512;
  int c = threadIdx.x & 63, rr = threadIdx.x >> 6;
#pragma unroll
  for (int i = 0; i < 16; ++i) {
    int r = rr + i * 4;
    t[r][c] = cvt_bf16(w[base + (size_t)(r0 + r) * 512 + c0 + c]);
  }
  __syncthreads();
#pragma unroll
  for (int i = 0; i < 16; ++i) {
    int r = rr + i * 4;
    wt[base + (size_t)(c0 + r) * 512 + r0 + c] = t[c][r];
  }
}

// (V,C) -> (C,V) fp32
__global__ void transposeSmall_kernel(const float* __restrict__ w, float* __restrict__ wt) {
  int idx = blockIdx.x * 256 + threadIdx.x;
  int v = idx >> 9;
  int c = idx & 511;
  wt[c * Vn + v] = w[idx];
}

__global__ void esum_kernel(const float* __restrict__ enc, float* __restrict__ Esum) {
  int p = blockIdx.x * 256 + threadIdx.x;
  float s = 0.f;
  for (int ss = 0; ss < Sn; ++ss) s += enc[(size_t)ss * Bn * En + p];
  Esum[p] = s;
}

// enc (S,B,E) fp32 -> encT (B,E,S) bf16
__global__ __launch_bounds__(256) void k_encT(const float* __restrict__ enc,
                                              unsigned short* __restrict__ encT) {
  __shared__ unsigned short t[64][66];
  int s0 = blockIdx.x * 64, e0 = blockIdx.y * 64, b = blockIdx.z;
  int c = threadIdx.x & 63, r0 = threadIdx.x >> 6;
#pragma unroll
  for (int i = 0; i < 16; ++i) {
    int r = r0 + i * 4;
    t[r][c] = cvt_bf16(enc[((size_t)(s0 + r) * Bn + b) * En + e0 + c]);
  }
  __syncthreads();
#pragma unroll
  for (int i = 0; i < 16; ++i) {
    int r = r0 + i * 4;
    encT[((size_t)b * En + e0 + r) * Sn + s0 + c] = t[c][r];
  }
}

// bd[l][e] = in2enc_b + lab2enc_b + sum_o i2e[e][o]*res_b[o]
// bh[l][c] = res_b + enc2in_b + inres_b
__global__ void k_biasprep(const float* __restrict__ i2e, const float* __restrict__ res_b,
                           const float* __restrict__ in2enc_b, const float* __restrict__ lab2enc_b,
                           const float* __restrict__ e2i_b, const float* __restrict__ inres_b,
                           float* __restrict__ bd, float* __restrict__ bh) {
  int idx = blockIdx.x * 256 + threadIdx.x;  // L*512
  int l = idx >> 9;
  float v = 0.f;
  const float* row = i2e + (size_t)idx * 512;
  const float* rb = res_b + l * 512;
  for (int c = 0; c < 512; ++c) v += row[c] * rb[c];
  bd[idx] = v + in2enc_b[idx] + lab2enc_b[idx];
  bh[idx] = res_b[idx] + e2i_b[idx] + inres_b[idx];
}

// ---------------- MFMA GEMM kernels ----------------

// W'[l] = i2e[l] @ res_w[l]  (via resT), bf16 out, blockIdx.z = layer
__global__ __launch_bounds__(256) void k_wfuse(const unsigned short* __restrict__ i2e,
                                               const unsigned short* __restrict__ resT,
                                               unsigned short* __restrict__ wf) {
  __shared__ unsigned short lsA[2][4096], lsB[2][4096];
  const int tid = threadIdx.x;
  const int lane = tid & 63, wave = tid >> 6;
  const int waveM = (wave >> 1) * 64, waveN = (wave & 1) * 64;
  const size_t base = (size_t)blockIdx.z * 512 * 512;
  const int m0 = blockIdx.x * 128, n0 = blockIdx.y * 128;
  f32x4 acc[4][4] = {};
  gemm16_pipe(i2e + base + (size_t)m0 * 512, 512, resT + base + (size_t)n0 * 512, 512, lsA, lsB,
              tid, lane, waveM, waveN, acc);
#pragma unroll
  for (int i = 0; i < 4; ++i)
#pragma unroll
    for (int j = 0; j < 4; ++j) {
      int col = n0 + waveN + j * 16 + (lane & 15);
#pragma unroll
      for (int r = 0; r < 4; ++r) {
        int row = m0 + waveM + i * 16 + (lane >> 4) * 4 + r;
        wf[base + (size_t)row * 512 + col] = cvt_bf16(acc[i][j][r]);
      }
    }
}

// GLU product only: glubf = (h*Wx + bx) * sigmoid(h*Wg + bg)
__global__ __launch_bounds__(256) void k_glu(const unsigned short* __restrict__ hd,
                                             const unsigned short* __restrict__ Wx,
                                             const unsigned short* __restrict__ Wg,
                                             const float* __restrict__ bx,
                                             const float* __restrict__ bg,
                                             unsigned short* __restrict__ glubf) {
  __shared__ unsigned short lsA[2][4096], lsX[2][4096], lsG[2][4096];
  const int tid = threadIdx.x;
  const int lane = tid & 63, wave = tid >> 6;
  const int waveM = (wave >> 1) * 64, waveN = (wave & 1) * 64;
  const int m0 = blockIdx.x * 128, n0 = blockIdx.y * 128;
  f32x4 aX[4][4] = {}, aG[4][4] = {};
  const unsigned short* Wx0 = Wx + (size_t)n0 * 1536;
  const unsigned short* Wg0 = Wg + (size_t)n0 * 1536;
  {
    const unsigned short* As = hd + ((ptrdiff_t)m0 - 2 * Bn) * 512;
    STAGE2(As, 512, lsA[0]);
    STAGE2(Wx0, 1536, lsX[0]);
    STAGE2(Wg0, 1536, lsG[0]);
  }
  int buf = 0;
  for (int s = 0; s < 48; ++s) {
    if (s < 47) {
      int sn = s + 1;
      int tap = sn >> 4, kk = (sn & 15) * 32;
      const unsigned short* As = hd + ((ptrdiff_t)m0 + (tap - 2) * Bn) * 512 + kk;
      STAGE2(As, 512, lsA[buf ^ 1]);
      STAGE2(Wx0 + sn * 32, 1536, lsX[buf ^ 1]);
      STAGE2(Wg0 + sn * 32, 1536, lsG[buf ^ 1]);
      pipe_wait<6>();
    } else {
      pipe_wait<0>();
    }
    mf_frags2(lsA[buf], lsX[buf], lsG[buf], lane, waveM, waveN, aX, aG);
    pipe_tail();
    buf ^= 1;
  }
#pragma unroll
  for (int i = 0; i < 4; ++i)
#pragma unroll
    for (int j = 0; j < 4; ++j) {
      int col = n0 + waveN + j * 16 + (lane & 15);
      float bxv = bx[col], bgv = bg[col];
#pragma unroll
      for (int r = 0; r < 4; ++r) {
        int row = m0 + waveM + i * 16 + (lane >> 4) * 4 + r;
        size_t o = (size_t)row * 512 + col;
        float xv = aX[i][j][r] + bxv;
        float gv = aG[i][j][r] + bgv;
        float sg = 1.f / (1.f + __expf(-gv));
        glubf[o] = cvt_bf16(xv * sg);
      }
    }
}

// triple-source GEMM, K=1536: out = A0@W0^T + A1@W1^T + A2@W2^T + bias (+ addbf), bf16 out
template <int ADDBF>
__global__ __launch_bounds__(256) void k_tri(const unsigned short* __restrict__ A0,
                                             const unsigned short* __restrict__ A1,
                                             const unsigned short* __restrict__ A2,
                                             const unsigned short* __restrict__ W0,
                                             const unsigned short* __restrict__ W1,
                                             const unsigned short* __restrict__ W2,
                                             const float* __restrict__ bias,
                                             const unsigned short* __restrict__ addbf,
                                             unsigned short* __restrict__ outbf) {
  __shared__ unsigned short lsA[2][4096], lsB[2][4096];
  const int tid = threadIdx.x;
  const int lane = tid & 63, wave = tid >> 6;
  const int waveM = (wave >> 1) * 64, waveN = (wave & 1) * 64;
  const int m0 = blockIdx.x * 128, n0 = blockIdx.y * 128;
  f32x4 acc[4][4] = {};
  const unsigned short* Asrc[3] = {A0 + (size_t)m0 * 512, A1 + (size_t)m0 * 512,
                                   A2 + (size_t)m0 * 512};
  const unsigned short* Wsrc[3] = {W0 + (size_t)n0 * 512, W1 + (size_t)n0 * 512,
                                   W2 + (size_t)n0 * 512};
  STAGE2(Asrc[0], 512, lsA[0]);
  STAGE2(Wsrc[0], 512, lsB[0]);
  int buf = 0;
  for (int s = 0; s < 48; ++s) {
    if (s < 47) {
      int sn = s + 1;
      int q = sn >> 4, kk = (sn & 15) * 32;
      STAGE2(Asrc[q] + kk, 512, lsA[buf ^ 1]);
      STAGE2(Wsrc[q] + kk, 512, lsB[buf ^ 1]);
      pipe_wait<4>();
    } else {
      pipe_wait<0>();
    }
    mf_frags(lsA[buf], lsB[buf], lane, waveM, waveN, acc);
    pipe_tail();
    buf ^= 1;
  }
#pragma unroll
  for (int i = 0; i < 4; ++i)
#pragma unroll
    for (int j = 0; j < 4; ++j) {
      int col = n0 + waveN + j * 16 + (lane & 15);
      float bb = bias[col];
#pragma unroll
      for (int r = 0; r < 4; ++r) {
        int row = m0 + waveM + i * 16 + (lane >> 4) * 4 + r;
        size_t o = (size_t)row * 512 + col;
        float v = acc[i][j][r] + bb;
        if constexpr (ADDBF) v += bf2f(addbf[o]);
        outbf[o] = cvt_bf16(v);
      }
    }
}

// Gram: M[b] = encT[b] @ encT[b]^T  (E x E, bf16 out)
__global__ __launch_bounds__(256) void k_gram(const unsigned short* __restrict__ encT,
                                              unsigned short* __restrict__ Mbf) {
  __shared__ unsigned short lsA[2][4096], lsB[2][4096];
  const int tid = threadIdx.x;
  const int lane = tid & 63, wave = tid >> 6;
  const int waveM = (wave >> 1) * 64, waveN = (wave & 1) * 64;
  const int b = blockIdx.z;
  const int e10 = blockIdx.x * 128, e20 = blockIdx.y * 128;
  f32x4 acc[4][4] = {};
  gemm16_pipe(encT + ((size_t)b * En + e10) * Sn, 512, encT + ((size_t)b * En + e20) * Sn, 512,
              lsA, lsB, tid, lane, waveM, waveN, acc);
#pragma unroll
  for (int i = 0; i < 4; ++i)
#pragma unroll
    for (int j = 0; j < 4; ++j) {
      int col = e20 + waveN + j * 16 + (lane & 15);
#pragma unroll
      for (int r = 0; r < 4; ++r) {
        int row = e10 + waveM + i * 16 + (lane >> 4) * 4 + r;
        Mbf[((size_t)b * En + row) * En + col] = cvt_bf16(acc[i][j][r]);
      }
    }
}

// den[row] = d[row] . Esum[b]
__global__ __launch_bounds__(256) void den_kernel(const unsigned short* __restrict__ d,
                                                  const float* __restrict__ Esum,
                                                  float* __restrict__ den) {
  int gtid = blockIdx.x * 256 + threadIdx.x;
  int row = gtid >> 6;
  int lane = threadIdx.x & 63;
  int b = row & 15;
  const unsigned short* dp = d + (size_t)row * 512 + lane * 8;
  const float* ep = Esum + b * 512 + lane * 8;
  float s = 0.f;
#pragma unroll
  for (int q = 0; q < 8; ++q) s += bf2f(dp[q]) * ep[q];
  for (int off = 32; off; off >>= 1) s += __shfl_down(s, off, 64);
  if (lane == 0) den[row] = s;
}

// ctx = (d @ M[b]) / den  -> bf16
__global__ __launch_bounds__(256) void k_ctx(const unsigned short* __restrict__ dbf,
                                             const unsigned short* __restrict__ Mbf,
                                             const float* __restrict__ den,
                                             unsigned short* __restrict__ ctxbf) {
  __shared__ unsigned short lsA[2][4096], lsB[2][4096];
  const int tid = threadIdx.x;
  const int lane = tid & 63, wave = tid >> 6;
  const int waveM = (wave >> 1) * 64, waveN = (wave & 1) * 64;
  const int b = blockIdx.z;
  const int t0 = blockIdx.x * 128, n0 = blockIdx.y * 128;
  f32x4 acc[4][4] = {};
  gemm16_pipe(dbf + ((size_t)t0 * Bn + b) * 512, 8192, Mbf + ((size_t)b * En + n0) * 512, 512,
              lsA, lsB, tid, lane, waveM, waveN, acc);
#pragma unroll
  for (int i = 0; i < 4; ++i) {
    float inv[4];
#pragma unroll
    for (int r = 0; r < 4; ++r) {
      int t = t0 + waveM + i * 16 + (lane >> 4) * 4 + r;
      inv[r] = 1.f / den[t * Bn + b];
    }
#pragma unroll
    for (int j = 0; j < 4; ++j) {
      int col = n0 + waveN + j * 16 + (lane & 15);
#pragma unroll
      for (int r = 0; r < 4; ++r) {
        int t = t0 + waveM + i * 16 + (lane >> 4) * 4 + r;
        ctxbf[((size_t)t * Bn + b) * 512 + col] = cvt_bf16(acc[i][j][r] * inv[r]);
      }
    }
  }
}

// out = h@opW^T + emb@orW^T + biases (fp32)
__global__ __launch_bounds__(256) void out_kernel(const unsigned short* __restrict__ hd,
                                                  const unsigned short* __restrict__ embd,
                                                  const float* __restrict__ opwT,
                                                  const float* __restrict__ opb,
                                                  const float* __restrict__ orwT,
                                                  const float* __restrict__ orb,
                                                  float* __restrict__ out) {
  __shared__ float rows[8][1024];
  int m0 = blockIdx.x * 8;
  int tid = threadIdx.x;
  for (int i = tid; i < 8 * 512; i += 256) {
    int r = i >> 9, c = i & 511;
    rows[r][c] = bf2f(hd[(size_t)(m0 + r) * 512 + c]);
    rows[r][512 + c] = bf2f(embd[(size_t)(m0 + r) * 512 + c]);
  }
  __syncthreads();
  int r = tid >> 5, v = tid & 31;
  float acc = opb[v] + orb[v];
  for (int c = 0; c < 512; ++c) acc += rows[r][c] * opwT[c * Vn + v];
  for (int c = 0; c < 512; ++c) acc += rows[r][512 + c] * orwT[c * Vn + v];
  out[(size_t)(m0 + r) * Vn + v] = acc;
}

// ---------------- host ----------------

extern "C" void kernel_launch(void* const* d_in, const int* in_sizes, int n_in,
                              void* d_out, int out_size, void* d_ws, size_t ws_size,
                              hipStream_t stream) {
  const int* labels = (const int*)d_in[0];
  const float* enc = (const float*)d_in[1];
  const float* labW = (const float*)d_in[2];
  const float* timeW = (const float*)d_in[3];
  const float* conv_glu_w = (const float*)d_in[4];
  const float* conv_glu_b = (const float*)d_in[5];
  const float* conv_id_w = (const float*)d_in[6];
  const float* conv_id_b = (const float*)d_in[7];
  const float* res_proj_w = (const float*)d_in[8];
  const float* res_proj_b = (const float*)d_in[9];
  const float* inres_w = (const float*)d_in[10];
  const float* inres_b = (const float*)d_in[11];
  const float* in2enc_w = (const float*)d_in[12];
  const float* in2enc_b = (const float*)d_in[13];
  const float* lab2enc_w = (const float*)d_in[14];
  const float* lab2enc_b = (const float*)d_in[15];
  const float* enc2in_w = (const float*)d_in[16];
  const float* enc2in_b = (const float*)d_in[17];
  const float* out_res_w = (const float*)d_in[18];
  const float* out_res_b = (const float*)d_in[19];
  const float* out_proj_w = (const float*)d_in[20];
  const float* out_proj_b = (const float*)d_in[21];
  float* out = (float*)d_out;

  char* cur = (char*)d_ws;
  auto alloc = [&](size_t bytes) {
    char* p = cur;
    cur += (bytes + 255) & ~(size_t)255;
    return p;
  };
  const size_t BIG = (size_t)MROWS * 512;
  const size_t WN = (size_t)Ln * Cn * Cn;  // per-weight total elems
  float* den = (float*)alloc(MROWS * 4);
  float* EsumB = (float*)alloc(Bn * En * 4);
  float* opwT = (float*)alloc(Cn * Vn * 4);
  float* orwT = (float*)alloc(Cn * Vn * 4);
  float* bd = (float*)alloc(Ln * 512 * 4);
  float* bh = (float*)alloc(Ln * 512 * 4);
  unsigned short* embp = (unsigned short*)alloc((PADE + BIG) * 2);
  unsigned short* h0p = (unsigned short*)alloc((PADE + BIG) * 2);
  unsigned short* h1p = (unsigned short*)alloc((PADE + BIG) * 2);
  unsigned short* glubf = (unsigned short*)alloc(BIG * 2);
  unsigned short* dbf = (unsigned short*)alloc(BIG * 2);
  unsigned short* ctxbf = (unsigned short*)alloc(BIG * 2);
  unsigned short* encT = (unsigned short*)alloc((size_t)Bn * En * Sn * 2);
  unsigned short* Mbf = (unsigned short*)alloc((size_t)Bn * En * En * 2);
  unsigned short* wres = (unsigned short*)alloc(WN * 2);
  unsigned short* resT = (unsigned short*)alloc(WN * 2);
  unsigned short* wfuse = (unsigned short*)alloc(WN * 2);
  unsigned short* wgx = (unsigned short*)alloc(WN * Kw * 2);
  unsigned short* wgg = (unsigned short*)alloc(WN * Kw * 2);
  unsigned short* w_i2e = (unsigned short*)alloc(WN * 2);
  unsigned short* w_l2e = (unsigned short*)alloc(WN * 2);
  unsigned short* w_inr = (unsigned short*)alloc(WN * 2);
  unsigned short* w_e2i = (unsigned short*)alloc(WN * 2);

  unsigned short* embd = embp + PADE;
  unsigned short* h0d = h0p + PADE;
  unsigned short* h1d = h1p + PADE;

  // setup
  emb_kernel<<<MROWS * 512 / 256, 256, 0, stream>>>(labels, labW, timeW, embd);
  k_zeropad<<<PADE / 256, 256, 0, stream>>>(embp, h0p, h1p);
  transposeW_kernel<<<WN * Kw / 256, 256, 0, stream>>>(conv_glu_w, wgx);
  transposeW_kernel<<<WN * Kw / 256, 256, 0, stream>>>(conv_id_w, wgg);
  cast_kernel<<<WN / 256, 256, 0, stream>>>(res_proj_w, wres, WN);
  cast_kernel<<<WN / 256, 256, 0, stream>>>(in2enc_w, w_i2e, WN);
  cast_kernel<<<WN / 256, 256, 0, stream>>>(lab2enc_w, w_l2e, WN);
  cast_kernel<<<WN / 256, 256, 0, stream>>>(inres_w, w_inr, WN);
  cast_kernel<<<WN / 256, 256, 0, stream>>>(enc2in_w, w_e2i, WN);
  k_tr512<<<dim3(8, 8, Ln), 256, 0, stream>>>(res_proj_w, resT);
  k_wfuse<<<dim3(4, 4, Ln), 256, 0, stream>>>(w_i2e, resT, wfuse);
  k_biasprep<<<Ln * 512 / 256, 256, 0, stream>>>(in2enc_w, res_proj_b, in2enc_b, lab2enc_b,
                                                 enc2in_b, inres_b, bd, bh);
  transposeSmall_kernel<<<Vn * Cn / 256, 256, 0, stream>>>(out_proj_w, opwT);
  transposeSmall_kernel<<<Vn * Cn / 256, 256, 0, stream>>>(out_res_w, orwT);
  esum_kernel<<<Bn * En / 256, 256, 0, stream>>>(enc, EsumB);
  k_encT<<<dim3(Sn / 64, En / 64, Bn), 256, 0, stream>>>(enc, encT);
  k_gram<<<dim3(En / 128, En / 128, Bn), 256, 0, stream>>>(encT, Mbf);

  dim3 ggrid(MROWS / 128, 512 / 128);
  const unsigned short* hdata = embd;
  unsigned short* hbufs[2] = {h0d, h1d};
  for (int l = 0; l < Ln; ++l) {
    const size_t wo = (size_t)l * Cn * Cn;
    const size_t wg = (size_t)l * Cn * Cn * Kw;
    // glubf = x * sigmoid(g)
    k_glu<<<ggrid, 256, 0, stream>>>(hdata, wgx + wg, wgg + wg, conv_glu_b + l * Cn,
                                     conv_id_b + l * Cn, glubf);
    // d = glu@i2e + h@W' + emb@l2e + bd    (res folded via W' = i2e@res_w)
    k_tri<0><<<ggrid, 256, 0, stream>>>(glubf, hdata, embd, w_i2e + wo, wfuse + wo, w_l2e + wo,
                                        bd + l * 512, nullptr, dbf);
    den_kernel<<<MROWS / 4, 256, 0, stream>>>(dbf, EsumB, den);
    k_ctx<<<dim3(Tn / 128, En / 128, Bn), 256, 0, stream>>>(dbf, Mbf, den, ctxbf);
    // h_out = h@res^T + ctx@e2i + emb@inres + bh + glu
    k_tri<1><<<ggrid, 256, 0, stream>>>(hdata, ctxbf, embd, wres + wo, w_e2i + wo, w_inr + wo,
                                        bh + l * 512, glubf, hbufs[l & 1]);
    hdata = hbufs[l & 1];
  }

  out_kernel<<<MROWS / 8, 256, 0, stream>>>(hdata, embd, opwT, out_proj_b, orwT, out_res_b, out);
}

// Round 4
// 829.665 us; speedup vs baseline: 6.6634x; 1.1183x over previous
//
#include <hip/hip_runtime.h>
#include <math.h>

#define Tn 1024
#define Bn 16
#define Sn 512
#define Vn 32
#define Cn 512
#define En 512
#define Ln 4
#define Kw 3
#define MROWS 16384
#define PADROWS 32
#define PADE (PADROWS * Cn)

typedef short bf16x8 __attribute__((ext_vector_type(8)));
typedef float f32x4 __attribute__((ext_vector_type(4)));

__device__ __forceinline__ unsigned short cvt_bf16(float x) {
  unsigned u = __builtin_bit_cast(unsigned, x);
  u = (u + 0x7FFFu + ((u >> 16) & 1u)) >> 16;
  return (unsigned short)u;
}
__device__ __forceinline__ float bf2f(unsigned short h) {
  unsigned u = ((unsigned)h) << 16;
  return __builtin_bit_cast(float, u);
}

#define GL16(g, l)                                                                     \
  __builtin_amdgcn_global_load_lds((const __attribute__((address_space(1))) void*)(g), \
                                   (__attribute__((address_space(3))) void*)(l), 16, 0, 0)

// counted-vmcnt pipeline barriers (T3/T4)
template <int N>
__device__ __forceinline__ void wait_vm_bar() {
  asm volatile("s_waitcnt vmcnt(%0)\n\ts_barrier" ::"i"(N) : "memory");
}
__device__ __forceinline__ void tail_bar() {
  asm volatile("s_waitcnt lgkmcnt(0)\n\ts_barrier" ::: "memory");
}

// stage one 128x32 bf16 tile (8KB) with 512 threads, swizzled global source
// (rule #21: linear LDS dst, inverse-swizzled src; read side applies same XOR)
#define STG(SRC, LD, BUF) \
  GL16((SRC) + (size_t)(tid >> 2) * (LD) + scol8, (char*)(BUF) + tid * 16)

// 64x32 wave tile: 4 A-frags x 2 B-frags, 8 MFMA
__device__ __forceinline__ void mf8(const unsigned short* As, const unsigned short* Bs, int ao,
                                    int bo, f32x4 acc[4][2]) {
  const char* ab = (const char*)As;
  const char* bb = (const char*)Bs;
  bf16x8 af[4], bfv[2];
#pragma unroll
  for (int i = 0; i < 4; ++i) af[i] = *(const bf16x8*)(ab + ao + i * 1024);
#pragma unroll
  for (int j = 0; j < 2; ++j) bfv[j] = *(const bf16x8*)(bb + bo + j * 1024);
#pragma unroll
  for (int i = 0; i < 4; ++i)
#pragma unroll
    for (int j = 0; j < 2; ++j)
      acc[i][j] = __builtin_amdgcn_mfma_f32_16x16x32_bf16(af[i], bfv[j], acc[i][j], 0, 0, 0);
}

// 32x32 wave tile, dual-B (X,G): 2 A-frags x 2+2 B-frags, 8 MFMA
__device__ __forceinline__ void mf8d(const unsigned short* As, const unsigned short* Xs,
                                     const unsigned short* Gs, int ao, int bo, f32x4 aX[2][2],
                                     f32x4 aG[2][2]) {
  const char* ab = (const char*)As;
  const char* xb = (const char*)Xs;
  const char* gb = (const char*)Gs;
  bf16x8 af[2], xf[2], gf[2];
#pragma unroll
  for (int i = 0; i < 2; ++i) af[i] = *(const bf16x8*)(ab + ao + i * 1024);
#pragma unroll
  for (int j = 0; j < 2; ++j) xf[j] = *(const bf16x8*)(xb + bo + j * 1024);
#pragma unroll
  for (int j = 0; j < 2; ++j) gf[j] = *(const bf16x8*)(gb + bo + j * 1024);
#pragma unroll
  for (int i = 0; i < 2; ++i)
#pragma unroll
    for (int j = 0; j < 2; ++j) {
      aX[i][j] = __builtin_amdgcn_mfma_f32_16x16x32_bf16(af[i], xf[j], aX[i][j], 0, 0, 0);
      aG[i][j] = __builtin_amdgcn_mfma_f32_16x16x32_bf16(af[i], gf[j], aG[i][j], 0, 0, 0);
    }
}

// 16-step (K=512) 3-deep pipelined GEMM core, 512 threads
__device__ __forceinline__ void pipe16(const unsigned short* A0, int lda,
                                       const unsigned short* B0, int ldb,
                                       unsigned short (*lsA)[4096], unsigned short (*lsB)[4096],
                                       int tid, int scol8, int ao, int bo, f32x4 acc[4][2]) {
  STG(A0, lda, lsA[0]);
  STG(B0, ldb, lsB[0]);
  STG(A0 + 32, lda, lsA[1]);
  STG(B0 + 32, ldb, lsB[1]);
  int cur = 0;
  for (int s = 0; s < 16; ++s) {
    if (s + 2 < 16) {
      int nxt = cur + 2;
      if (nxt >= 3) nxt -= 3;
      STG(A0 + (s + 2) * 32, lda, lsA[nxt]);
      STG(B0 + (s + 2) * 32, ldb, lsB[nxt]);
      wait_vm_bar<4>();
    } else if (s + 1 < 16) {
      wait_vm_bar<2>();
    } else {
      wait_vm_bar<0>();
    }
    __builtin_amdgcn_s_setprio(1);
    mf8(lsA[cur], lsB[cur], ao, bo, acc);
    __builtin_amdgcn_s_setprio(0);
    tail_bar();
    ++cur;
    if (cur == 3) cur = 0;
  }
}

// ---------------- setup kernels ----------------

__global__ __launch_bounds__(256) void emb_kernel(const int* __restrict__ labels,
                                                  const float* __restrict__ labW,
                                                  const float* __restrict__ timeW,
                                                  unsigned short* __restrict__ embd) {
  int idx = blockIdx.x * 256 + threadIdx.x;
  int dd = idx & 511;
  int m = idx >> 9;
  int t = m >> 4;
  embd[idx] = cvt_bf16(labW[labels[m] * 512 + dd] + timeW[t * 512 + dd]);
}

__global__ void k_zeropad(unsigned short* a, unsigned short* b, unsigned short* c) {
  int i = blockIdx.x * 256 + threadIdx.x;
  a[i] = 0; b[i] = 0; c[i] = 0;
}

// conv weights (L,C,C,K) fp32 -> (L,C,K*C) bf16
__global__ void transposeW_kernel(const float* __restrict__ w, unsigned short* __restrict__ wt) {
  int idx = blockIdx.x * 256 + threadIdx.x;
  int k = idx % Kw;
  int tmp = idx / Kw;
  int c = tmp & 511;
  tmp >>= 9;
  int o = tmp & 511;
  int l = tmp >> 9;
  wt[(((size_t)l * Cn + o) * Kw + k) * Cn + c] = cvt_bf16(w[idx]);
}

__global__ void cast_kernel(const float* __restrict__ src, unsigned short* __restrict__ dst,
                            int n) {
  int i = blockIdx.x * 256 + threadIdx.x;
  if (i < n) dst[i] = cvt_bf16(src[i]);
}

// per-layer 512x512 transpose, fp32 -> bf16 (for res_w^T)
__global__ __launch_bounds__(256) void k_tr512(const float* __restrict__ w,
                                               unsigned short* __restrict__ wt) {
  __shared__ unsigned short t[64][65];
  int r0 = blockIdx.x * 64, c0 = blockIdx.y * 64;
  size_t base = (size_t)blockIdx.z * 512 * 512;
  int c = threadIdx.x & 63, rr = threadIdx.x >> 6;
#pragma unroll
  for (int i = 0; i < 16; ++i) {
    int r = rr + i * 4;
    t[r][c] = cvt_bf16(w[base + (size_t)(r0 + r) * 512 + c0 + c]);
  }
  __syncthreads();
#pragma unroll
  for (int i = 0; i < 16; ++i) {
    int r = rr + i * 4;
    wt[base + (size_t)(c0 + r) * 512 + r0 + c] = t[c][r];
  }
}

// (V,C) -> (C,V) fp32
__global__ void transposeSmall_kernel(const float* __restrict__ w, float* __restrict__ wt) {
  int idx = blockIdx.x * 256 + threadIdx.x;
  int v = idx >> 9;
  int c = idx & 511;
  wt[c * Vn + v] = w[idx];
}

__global__ void esum_kernel(const float* __restrict__ enc, float* __restrict__ Esum) {
  int p = blockIdx.x * 256 + threadIdx.x;
  float s = 0.f;
  for (int ss = 0; ss < Sn; ++ss) s += enc[(size_t)ss * Bn * En + p];
  Esum[p] = s;
}

// enc (S,B,E) fp32 -> encT (B,E,S) bf16
__global__ __launch_bounds__(256) void k_encT(const float* __restrict__ enc,
                                              unsigned short* __restrict__ encT) {
  __shared__ unsigned short t[64][66];
  int s0 = blockIdx.x * 64, e0 = blockIdx.y * 64, b = blockIdx.z;
  int c = threadIdx.x & 63, r0 = threadIdx.x >> 6;
#pragma unroll
  for (int i = 0; i < 16; ++i) {
    int r = r0 + i * 4;
    t[r][c] = cvt_bf16(enc[((size_t)(s0 + r) * Bn + b) * En + e0 + c]);
  }
  __syncthreads();
#pragma unroll
  for (int i = 0; i < 16; ++i) {
    int r = r0 + i * 4;
    encT[((size_t)b * En + e0 + r) * Sn + s0 + c] = t[c][r];
  }
}

__global__ void k_biasprep(const float* __restrict__ i2e, const float* __restrict__ res_b,
                           const float* __restrict__ in2enc_b, const float* __restrict__ lab2enc_b,
                           const float* __restrict__ e2i_b, const float* __restrict__ inres_b,
                           float* __restrict__ bd, float* __restrict__ bh) {
  int idx = blockIdx.x * 256 + threadIdx.x;  // L*512
  int l = idx >> 9;
  float v = 0.f;
  const float* row = i2e + (size_t)idx * 512;
  const float* rb = res_b + l * 512;
  for (int c = 0; c < 512; ++c) v += row[c] * rb[c];
  bd[idx] = v + in2enc_b[idx] + lab2enc_b[idx];
  bh[idx] = res_b[idx] + e2i_b[idx] + inres_b[idx];
}

// ---------------- MFMA GEMM kernels (512 threads, 8 waves) ----------------

#define PREAMBLE_8W                                          \
  const int tid = threadIdx.x;                               \
  const int lane = tid & 63, wave = tid >> 6;                \
  const int r15 = lane & 15;                                 \
  const int sq = ((lane >> 4) ^ ((r15 >> 1) & 3)) << 4;      \
  const int scol8 = (((tid & 3) ^ ((tid >> 3) & 3))) << 3;

// W'[l] = i2e[l] @ res_w[l]  (via resT), bf16 out
__global__ __launch_bounds__(512, 4) void k_wfuse(const unsigned short* __restrict__ i2e,
                                                  const unsigned short* __restrict__ resT,
                                                  unsigned short* __restrict__ wf) {
  __shared__ unsigned short lsA[3][4096], lsB[3][4096];
  PREAMBLE_8W
  const int waveM = (wave >> 2) * 64, waveN = (wave & 3) * 32;
  const int ao = (waveM + r15) * 64 + sq, bo = (waveN + r15) * 64 + sq;
  const size_t base = (size_t)blockIdx.z * 512 * 512;
  const int m0 = blockIdx.x * 128, n0 = blockIdx.y * 128;
  f32x4 acc[4][2] = {};
  pipe16(i2e + base + (size_t)m0 * 512, 512, resT + base + (size_t)n0 * 512, 512, lsA, lsB, tid,
         scol8, ao, bo, acc);
#pragma unroll
  for (int i = 0; i < 4; ++i)
#pragma unroll
    for (int j = 0; j < 2; ++j) {
      int col = n0 + waveN + j * 16 + r15;
#pragma unroll
      for (int r = 0; r < 4; ++r) {
        int row = m0 + waveM + i * 16 + (lane >> 4) * 4 + r;
        wf[base + (size_t)row * 512 + col] = cvt_bf16(acc[i][j][r]);
      }
    }
}

// Gram: M[b] = encT[b] @ encT[b]^T
__global__ __launch_bounds__(512, 4) void k_gram(const unsigned short* __restrict__ encT,
                                                 unsigned short* __restrict__ Mbf) {
  __shared__ unsigned short lsA[3][4096], lsB[3][4096];
  PREAMBLE_8W
  const int waveM = (wave >> 2) * 64, waveN = (wave & 3) * 32;
  const int ao = (waveM + r15) * 64 + sq, bo = (waveN + r15) * 64 + sq;
  const int b = blockIdx.z;
  const int e10 = blockIdx.x * 128, e20 = blockIdx.y * 128;
  f32x4 acc[4][2] = {};
  pipe16(encT + ((size_t)b * En + e10) * Sn, 512, encT + ((size_t)b * En + e20) * Sn, 512, lsA,
         lsB, tid, scol8, ao, bo, acc);
#pragma unroll
  for (int i = 0; i < 4; ++i)
#pragma unroll
    for (int j = 0; j < 2; ++j) {
      int col = e20 + waveN + j * 16 + r15;
#pragma unroll
      for (int r = 0; r < 4; ++r) {
        int row = e10 + waveM + i * 16 + (lane >> 4) * 4 + r;
        Mbf[((size_t)b * En + row) * En + col] = cvt_bf16(acc[i][j][r]);
      }
    }
}

// ctx = (d @ M[b]) / den  -> bf16
__global__ __launch_bounds__(512, 4) void k_ctx(const unsigned short* __restrict__ dbf,
                                                const unsigned short* __restrict__ Mbf,
                                                const float* __restrict__ den,
                                                unsigned short* __restrict__ ctxbf) {
  __shared__ unsigned short lsA[3][4096], lsB[3][4096];
  PREAMBLE_8W
  const int waveM = (wave >> 2) * 64, waveN = (wave & 3) * 32;
  const int ao = (waveM + r15) * 64 + sq, bo = (waveN + r15) * 64 + sq;
  const int b = blockIdx.z;
  const int t0 = blockIdx.x * 128, n0 = blockIdx.y * 128;
  f32x4 acc[4][2] = {};
  pipe16(dbf + ((size_t)t0 * Bn + b) * 512, 8192, Mbf + ((size_t)b * En + n0) * 512, 512, lsA,
         lsB, tid, scol8, ao, bo, acc);
#pragma unroll
  for (int i = 0; i < 4; ++i) {
    float inv[4];
#pragma unroll
    for (int r = 0; r < 4; ++r) {
      int t = t0 + waveM + i * 16 + (lane >> 4) * 4 + r;
      inv[r] = 1.f / den[t * Bn + b];
    }
#pragma unroll
    for (int j = 0; j < 2; ++j) {
      int col = n0 + waveN + j * 16 + r15;
#pragma unroll
      for (int r = 0; r < 4; ++r) {
        int t = t0 + waveM + i * 16 + (lane >> 4) * 4 + r;
        ctxbf[((size_t)t * Bn + b) * 512 + col] = cvt_bf16(acc[i][j][r] * inv[r]);
      }
    }
  }
}

// triple-source GEMM, K=1536: out = A0@W0^T + A1@W1^T + A2@W2^T + bias (+ addbf), bf16 out
template <int ADDBF>
__global__ __launch_bounds__(512, 4) void k_tri(const unsigned short* __restrict__ A0,
                                                const unsigned short* __restrict__ A1,
                                                const unsigned short* __restrict__ A2,
                                                const unsigned short* __restrict__ W0,
                                                const unsigned short* __restrict__ W1,
                                                const unsigned short* __restrict__ W2,
                                                const float* __restrict__ bias,
                                                const unsigned short* __restrict__ addbf,
                                                unsigned short* __restrict__ outbf) {
  __shared__ unsigned short lsA[3][4096], lsB[3][4096];
  PREAMBLE_8W
  const int waveM = (wave >> 2) * 64, waveN = (wave & 3) * 32;
  const int ao = (waveM + r15) * 64 + sq, bo = (waveN + r15) * 64 + sq;
  const int m0 = blockIdx.x * 128, n0 = blockIdx.y * 128;
  f32x4 acc[4][2] = {};
  const unsigned short* Asrc[3] = {A0 + (size_t)m0 * 512, A1 + (size_t)m0 * 512,
                                   A2 + (size_t)m0 * 512};
  const unsigned short* Wsrc[3] = {W0 + (size_t)n0 * 512, W1 + (size_t)n0 * 512,
                                   W2 + (size_t)n0 * 512};
  STG(Asrc[0], 512, lsA[0]);
  STG(Wsrc[0], 512, lsB[0]);
  STG(Asrc[0] + 32, 512, lsA[1]);
  STG(Wsrc[0] + 32, 512, lsB[1]);
  int cur = 0;
  for (int s = 0; s < 48; ++s) {
    if (s + 2 < 48) {
      int sn = s + 2;
      int nxt = cur + 2;
      if (nxt >= 3) nxt -= 3;
      int q = sn >> 4, kk = (sn & 15) << 5;
      STG(Asrc[q] + kk, 512, lsA[nxt]);
      STG(Wsrc[q] + kk, 512, lsB[nxt]);
      wait_vm_bar<4>();
    } else if (s + 1 < 48) {
      wait_vm_bar<2>();
    } else {
      wait_vm_bar<0>();
    }
    __builtin_amdgcn_s_setprio(1);
    mf8(lsA[cur], lsB[cur], ao, bo, acc);
    __builtin_amdgcn_s_setprio(0);
    tail_bar();
    ++cur;
    if (cur == 3) cur = 0;
  }
#pragma unroll
  for (int i = 0; i < 4; ++i)
#pragma unroll
    for (int j = 0; j < 2; ++j) {
      int col = n0 + waveN + j * 16 + r15;
      float bb = bias[col];
#pragma unroll
      for (int r = 0; r < 4; ++r) {
        int row = m0 + waveM + i * 16 + (lane >> 4) * 4 + r;
        size_t o = (size_t)row * 512 + col;
        float v = acc[i][j][r] + bb;
        if constexpr (ADDBF) v += bf2f(addbf[o]);
        outbf[o] = cvt_bf16(v);
      }
    }
}

// GLU: glubf = (h*Wx + bx) * sigmoid(h*Wg + bg); 128x64 block, causal K=1536
__global__ __launch_bounds__(512, 4) void k_glu(const unsigned short* __restrict__ hd,
                                                const unsigned short* __restrict__ Wx,
                                                const unsigned short* __restrict__ Wg,
                                                const float* __restrict__ bx,
                                                const float* __restrict__ bg,
                                                unsigned short* __restrict__ glubf) {
  __shared__ unsigned short lsA[3][4096], lsX[3][2048], lsG[3][2048];
  PREAMBLE_8W
  const int waveM = (wave >> 1) * 32, waveN = (wave & 1) * 32;  // 4x2 waves of 32x32
  const int ao = (waveM + r15) * 64 + sq, bo = (waveN + r15) * 64 + sq;
  const int m0 = blockIdx.x * 128, n0 = blockIdx.y * 64;
  f32x4 aX[2][2] = {}, aG[2][2] = {};
  // X/G staged by wave halves: waves 0-3 -> X, waves 4-7 -> G (64x32 tiles, 4KB)
  const int tidh = tid & 255;
  const int rowx = tidh >> 2;
  const int scolx = (((tidh & 3) ^ ((tidh >> 3) & 3))) << 3;
  const unsigned short* WB =
      ((wave < 4) ? Wx : Wg) + ((size_t)n0 + rowx) * 1536 + scolx;
  unsigned short(*lsW)[2048] = (wave < 4) ? lsX : lsG;
#define GLU_STAGE(SN, NB)                                                                   \
  do {                                                                                      \
    int tap_ = (SN) >> 4, kk_ = ((SN) & 15) << 5;                                           \
    STG(hd + ((ptrdiff_t)m0 + (tap_ - 2) * Bn) * 512 + kk_, 512, lsA[NB]);                  \
    GL16(WB + (SN) * 32, (char*)lsW[NB] + tidh * 16);                                       \
  } while (0)
  GLU_STAGE(0, 0);
  GLU_STAGE(1, 1);
  int cur = 0;
  for (int s = 0; s < 48; ++s) {
    if (s + 2 < 48) {
      int nxt = cur + 2;
      if (nxt >= 3) nxt -= 3;
      GLU_STAGE(s + 2, nxt);
      wait_vm_bar<4>();
    } else if (s + 1 < 48) {
      wait_vm_bar<2>();
    } else {
      wait_vm_bar<0>();
    }
    __builtin_amdgcn_s_setprio(1);
    mf8d(lsA[cur], lsX[cur], lsG[cur], ao, bo, aX, aG);
    __builtin_amdgcn_s_setprio(0);
    tail_bar();
    ++cur;
    if (cur == 3) cur = 0;
  }
#undef GLU_STAGE
#pragma unroll
  for (int i = 0; i < 2; ++i)
#pragma unroll
    for (int j = 0; j < 2; ++j) {
      int col = n0 + waveN + j * 16 + r15;
      float bxv = bx[col], bgv = bg[col];
#pragma unroll
      for (int r = 0; r < 4; ++r) {
        int row = m0 + waveM + i * 16 + (lane >> 4) * 4 + r;
        size_t o = (size_t)row * 512 + col;
        float xv = aX[i][j][r] + bxv;
        float gv = aG[i][j][r] + bgv;
        float sg = 1.f / (1.f + __expf(-gv));
        glubf[o] = cvt_bf16(xv * sg);
      }
    }
}

// den[row] = d[row] . Esum[b]
__global__ __launch_bounds__(256) void den_kernel(const unsigned short* __restrict__ d,
                                                  const float* __restrict__ Esum,
                                                  float* __restrict__ den) {
  int gtid = blockIdx.x * 256 + threadIdx.x;
  int row = gtid >> 6;
  int lane = threadIdx.x & 63;
  int b = row & 15;
  const unsigned short* dp = d + (size_t)row * 512 + lane * 8;
  const float* ep = Esum + b * 512 + lane * 8;
  float s = 0.f;
#pragma unroll
  for (int q = 0; q < 8; ++q) s += bf2f(dp[q]) * ep[q];
  for (int off = 32; off; off >>= 1) s += __shfl_down(s, off, 64);
  if (lane == 0) den[row] = s;
}

// out = h@opW^T + emb@orW^T + biases (fp32)
__global__ __launch_bounds__(256) void out_kernel(const unsigned short* __restrict__ hd,
                                                  const unsigned short* __restrict__ embd,
                                                  const float* __restrict__ opwT,
                                                  const float* __restrict__ opb,
                                                  const float* __restrict__ orwT,
                                                  const float* __restrict__ orb,
                                                  float* __restrict__ out) {
  __shared__ float rows[8][1024];
  int m0 = blockIdx.x * 8;
  int tid = threadIdx.x;
  for (int i = tid; i < 8 * 512; i += 256) {
    int r = i >> 9, c = i & 511;
    rows[r][c] = bf2f(hd[(size_t)(m0 + r) * 512 + c]);
    rows[r][512 + c] = bf2f(embd[(size_t)(m0 + r) * 512 + c]);
  }
  __syncthreads();
  int r = tid >> 5, v = tid & 31;
  float acc = opb[v] + orb[v];
  for (int c = 0; c < 512; ++c) acc += rows[r][c] * opwT[c * Vn + v];
  for (int c = 0; c < 512; ++c) acc += rows[r][512 + c] * orwT[c * Vn + v];
  out[(size_t)(m0 + r) * Vn + v] = acc;
}

// ---------------- host ----------------

extern "C" void kernel_launch(void* const* d_in, const int* in_sizes, int n_in,
                              void* d_out, int out_size, void* d_ws, size_t ws_size,
                              hipStream_t stream) {
  const int* labels = (const int*)d_in[0];
  const float* enc = (const float*)d_in[1];
  const float* labW = (const float*)d_in[2];
  const float* timeW = (const float*)d_in[3];
  const float* conv_glu_w = (const float*)d_in[4];
  const float* conv_glu_b = (const float*)d_in[5];
  const float* conv_id_w = (const float*)d_in[6];
  const float* conv_id_b = (const float*)d_in[7];
  const float* res_proj_w = (const float*)d_in[8];
  const float* res_proj_b = (const float*)d_in[9];
  const float* inres_w = (const float*)d_in[10];
  const float* inres_b = (const float*)d_in[11];
  const float* in2enc_w = (const float*)d_in[12];
  const float* in2enc_b = (const float*)d_in[13];
  const float* lab2enc_w = (const float*)d_in[14];
  const float* lab2enc_b = (const float*)d_in[15];
  const float* enc2in_w = (const float*)d_in[16];
  const float* enc2in_b = (const float*)d_in[17];
  const float* out_res_w = (const float*)d_in[18];
  const float* out_res_b = (const float*)d_in[19];
  const float* out_proj_w = (const float*)d_in[20];
  const float* out_proj_b = (const float*)d_in[21];
  float* out = (float*)d_out;

  char* cur = (char*)d_ws;
  auto alloc = [&](size_t bytes) {
    char* p = cur;
    cur += (bytes + 255) & ~(size_t)255;
    return p;
  };
  const size_t BIG = (size_t)MROWS * 512;
  const size_t WN = (size_t)Ln * Cn * Cn;
  float* den = (float*)alloc(MROWS * 4);
  float* EsumB = (float*)alloc(Bn * En * 4);
  float* opwT = (float*)alloc(Cn * Vn * 4);
  float* orwT = (float*)alloc(Cn * Vn * 4);
  float* bd = (float*)alloc(Ln * 512 * 4);
  float* bh = (float*)alloc(Ln * 512 * 4);
  unsigned short* embp = (unsigned short*)alloc((PADE + BIG) * 2);
  unsigned short* h0p = (unsigned short*)alloc((PADE + BIG) * 2);
  unsigned short* h1p = (unsigned short*)alloc((PADE + BIG) * 2);
  unsigned short* glubf = (unsigned short*)alloc(BIG * 2);
  unsigned short* dbf = (unsigned short*)alloc(BIG * 2);
  unsigned short* ctxbf = (unsigned short*)alloc(BIG * 2);
  unsigned short* encT = (unsigned short*)alloc((size_t)Bn * En * Sn * 2);
  unsigned short* Mbf = (unsigned short*)alloc((size_t)Bn * En * En * 2);
  unsigned short* wres = (unsigned short*)alloc(WN * 2);
  unsigned short* resT = (unsigned short*)alloc(WN * 2);
  unsigned short* wfuse = (unsigned short*)alloc(WN * 2);
  unsigned short* wgx = (unsigned short*)alloc(WN * Kw * 2);
  unsigned short* wgg = (unsigned short*)alloc(WN * Kw * 2);
  unsigned short* w_i2e = (unsigned short*)alloc(WN * 2);
  unsigned short* w_l2e = (unsigned short*)alloc(WN * 2);
  unsigned short* w_inr = (unsigned short*)alloc(WN * 2);
  unsigned short* w_e2i = (unsigned short*)alloc(WN * 2);

  unsigned short* embd = embp + PADE;
  unsigned short* h0d = h0p + PADE;
  unsigned short* h1d = h1p + PADE;

  // setup
  emb_kernel<<<MROWS * 512 / 256, 256, 0, stream>>>(labels, labW, timeW, embd);
  k_zeropad<<<PADE / 256, 256, 0, stream>>>(embp, h0p, h1p);
  transposeW_kernel<<<WN * Kw / 256, 256, 0, stream>>>(conv_glu_w, wgx);
  transposeW_kernel<<<WN * Kw / 256, 256, 0, stream>>>(conv_id_w, wgg);
  cast_kernel<<<WN / 256, 256, 0, stream>>>(res_proj_w, wres, WN);
  cast_kernel<<<WN / 256, 256, 0, stream>>>(in2enc_w, w_i2e, WN);
  cast_kernel<<<WN / 256, 256, 0, stream>>>(lab2enc_w, w_l2e, WN);
  cast_kernel<<<WN / 256, 256, 0, stream>>>(inres_w, w_inr, WN);
  cast_kernel<<<WN / 256, 256, 0, stream>>>(enc2in_w, w_e2i, WN);
  k_tr512<<<dim3(8, 8, Ln), 256, 0, stream>>>(res_proj_w, resT);
  k_wfuse<<<dim3(4, 4, Ln), 512, 0, stream>>>(w_i2e, resT, wfuse);
  k_biasprep<<<Ln * 512 / 256, 256, 0, stream>>>(in2enc_w, res_proj_b, in2enc_b, lab2enc_b,
                                                 enc2in_b, inres_b, bd, bh);
  transposeSmall_kernel<<<Vn * Cn / 256, 256, 0, stream>>>(out_proj_w, opwT);
  transposeSmall_kernel<<<Vn * Cn / 256, 256, 0, stream>>>(out_res_w, orwT);
  esum_kernel<<<Bn * En / 256, 256, 0, stream>>>(enc, EsumB);
  k_encT<<<dim3(Sn / 64, En / 64, Bn), 256, 0, stream>>>(enc, encT);
  k_gram<<<dim3(4, 4, Bn), 512, 0, stream>>>(encT, Mbf);

  dim3 tgrid(MROWS / 128, 4);
  dim3 ggrid(MROWS / 128, 8);
  const unsigned short* hdata = embd;
  unsigned short* hbufs[2] = {h0d, h1d};
  for (int l = 0; l < Ln; ++l) {
    const size_t wo = (size_t)l * Cn * Cn;
    const size_t wg = (size_t)l * Cn * Cn * Kw;
    k_glu<<<ggrid, 512, 0, stream>>>(hdata, wgx + wg, wgg + wg, conv_glu_b + l * Cn,
                                     conv_id_b + l * Cn, glubf);
    k_tri<0><<<tgrid, 512, 0, stream>>>(glubf, hdata, embd, w_i2e + wo, wfuse + wo, w_l2e + wo,
                                        bd + l * 512, nullptr, dbf);
    den_kernel<<<MROWS / 4, 256, 0, stream>>>(dbf, EsumB, den);
    k_ctx<<<dim3(Tn / 128, 4, Bn), 512, 0, stream>>>(dbf, Mbf, den, ctxbf);
    k_tri<1><<<tgrid, 512, 0, stream>>>(hdata, ctxbf, embd, wres + wo, w_e2i + wo, w_inr + wo,
                                        bh + l * 512, glubf, hbufs[l & 1]);
    hdata = hbufs[l & 1];
  }

  out_kernel<<<MROWS / 8, 256, 0, stream>>>(hdata, embd, opwT, out_proj_b, orwT, out_res_b, out);
}

// Round 6
// 729.908 us; speedup vs baseline: 7.5741x; 1.1367x over previous
//
#include <hip/hip_runtime.h>
#include <math.h>

#define Tn 1024
#define Bn 16
#define Sn 512
#define Vn 32
#define Cn 512
#define En 512
#define Ln 4
#define Kw 3
#define MROWS 16384
#define PADROWS 32
#define PADE (PADROWS * Cn)

typedef short bf16x8 __attribute__((ext_vector_type(8)));
typedef float f32x4 __attribute__((ext_vector_type(4)));

__device__ __forceinline__ unsigned short cvt_bf16(float x) {
  unsigned u = __builtin_bit_cast(unsigned, x);
  u = (u + 0x7FFFu + ((u >> 16) & 1u)) >> 16;
  return (unsigned short)u;
}
__device__ __forceinline__ float bf2f(unsigned short h) {
  unsigned u = ((unsigned)h) << 16;
  return __builtin_bit_cast(float, u);
}

#define GL16(g, l)                                                                     \
  __builtin_amdgcn_global_load_lds((const __attribute__((address_space(1))) void*)(g), \
                                   (__attribute__((address_space(3))) void*)(l), 16, 0, 0)

template <int N>
__device__ __forceinline__ void wait_vm_bar() {
  asm volatile("s_waitcnt vmcnt(%0)\n\ts_barrier" ::"i"(N) : "memory");
}
__device__ __forceinline__ void tail_bar() {
  asm volatile("s_waitcnt lgkmcnt(0)\n\ts_barrier" ::: "memory");
}

__device__ __forceinline__ const unsigned short* seg_sel(const unsigned short* s0,
                                                         const unsigned short* s1,
                                                         const unsigned short* s2, int q) {
  const unsigned short* r = s0;
  r = (q == 1) ? s1 : r;
  r = (q == 2) ? s2 : r;
  return r;
}

// ---------------- unified 128x128 BK=64 pipelined MFMA GEMM ----------------
// EPI: 0 glu-pair (interleaved Wcat, out 512 cols)
//      1 bias + bf16      2 bias + addbf + bf16      3 ctx (div den)      4 plain bf16
template <int EPI, int NKT>
__global__ __launch_bounds__(512, 4) void g2(
    const unsigned short* __restrict__ a0, const unsigned short* __restrict__ a1,
    const unsigned short* __restrict__ a2, int ald, size_t az,
    const unsigned short* __restrict__ b0, const unsigned short* __restrict__ b1,
    const unsigned short* __restrict__ b2, int bld, size_t bz,
    const float* __restrict__ bias, const unsigned short* __restrict__ addbf,
    const float* __restrict__ dden, unsigned short* __restrict__ out, int old_, size_t oz) {
  __shared__ char SA[32768], SB[32768];
  const int tid = threadIdx.x;
  const int lane = tid & 63, wave = tid >> 6;
  const int r15 = lane & 15;
  const int sq = ((lane >> 4) ^ ((r15 >> 1) & 3)) << 4;
  const int waveM = (wave >> 2) << 6;  // 0 / 64
  const int waveN = (wave & 3) << 5;   // 0..96
  const int m0 = blockIdx.x * 128, n0 = blockIdx.y * 128;
  const int z = blockIdx.z;
  const unsigned short* A0 = a0 + (size_t)z * az;
  const unsigned short* A1 = a1 + (size_t)z * az;
  const unsigned short* A2 = a2 + (size_t)z * az;
  const unsigned short* B0 = b0 + (size_t)z * bz;
  const unsigned short* B1 = b1 + (size_t)z * bz;
  const unsigned short* B2 = b2 + (size_t)z * bz;
  const int strow = tid >> 2;
  const int stcol = ((tid & 3) ^ ((tid >> 3) & 3)) << 3;
  const int lofs = tid * 16;
  f32x4 acc[4][2] = {};

#define STAGE_T(KT, SL)                                                                  \
  do {                                                                                   \
    const unsigned short* ab_ = seg_sel(A0, A1, A2, (KT) >> 3) +                         \
                                (size_t)(m0 + strow) * ald + (((KT) & 7) << 6) + stcol;  \
    const unsigned short* bb_ = seg_sel(B0, B1, B2, (KT) >> 3) +                         \
                                (size_t)(n0 + strow) * bld + (((KT) & 7) << 6) + stcol;  \
    GL16(ab_, SA + (SL) * 16384 + lofs);                                                 \
    GL16(ab_ + 32, SA + (SL) * 16384 + 8192 + lofs);                                     \
    GL16(bb_, SB + (SL) * 16384 + lofs);                                                 \
    GL16(bb_ + 32, SB + (SL) * 16384 + 8192 + lofs);                                     \
  } while (0)

  STAGE_T(0, 0);
  for (int kt = 0; kt < NKT; ++kt) {
    const int sl = kt & 1;
    if (kt + 1 < NKT) {
      STAGE_T(kt + 1, sl ^ 1);
      wait_vm_bar<4>();
    } else {
      wait_vm_bar<0>();
    }
    const char* abase = SA + sl * 16384 + (waveM + r15) * 64 + sq;
    const char* bbase = SB + sl * 16384 + (waveN + r15) * 64 + sq;
    __builtin_amdgcn_s_setprio(1);
#pragma unroll
    for (int kp = 0; kp < 2; ++kp) {
      bf16x8 af[4], bfv[2];
#pragma unroll
      for (int i = 0; i < 4; ++i) af[i] = *(const bf16x8*)(abase + kp * 8192 + i * 1024);
#pragma unroll
      for (int j = 0; j < 2; ++j) bfv[j] = *(const bf16x8*)(bbase + kp * 8192 + j * 1024);
#pragma unroll
      for (int i = 0; i < 4; ++i)
#pragma unroll
        for (int j = 0; j < 2; ++j)
          acc[i][j] = __builtin_amdgcn_mfma_f32_16x16x32_bf16(af[i], bfv[j], acc[i][j], 0, 0, 0);
    }
    __builtin_amdgcn_s_setprio(0);
    tail_bar();
  }
#undef STAGE_T

  const int q4 = (lane >> 4) << 2;
#pragma unroll
  for (int i = 0; i < 4; ++i) {
    int row = m0 + waveM + i * 16 + q4;
    if constexpr (EPI == 0) {
      int xcol = ((n0 + waveN) >> 1) + r15;
      float bx = bias[n0 + waveN + r15];
      float bg = bias[n0 + waveN + 16 + r15];
#pragma unroll
      for (int rr = 0; rr < 4; ++rr) {
        float xv = acc[i][0][rr] + bx;
        float gv = acc[i][1][rr] + bg;
        float sg = 1.f / (1.f + __expf(-gv));
        out[(size_t)(row + rr) * 512 + xcol] = cvt_bf16(xv * sg);
      }
    } else if constexpr (EPI == 3) {
#pragma unroll
      for (int rr = 0; rr < 4; ++rr) {
        float inv = 1.f / dden[z + (size_t)(row + rr) * 16];
#pragma unroll
        for (int j = 0; j < 2; ++j) {
          int col = n0 + waveN + j * 16 + r15;
          out[(size_t)z * oz + (size_t)(row + rr) * old_ + col] = cvt_bf16(acc[i][j][rr] * inv);
        }
      }
    } else {
#pragma unroll
      for (int j = 0; j < 2; ++j) {
        int col = n0 + waveN + j * 16 + r15;
        float bb = (EPI == 4) ? 0.f : bias[col];
#pragma unroll
        for (int rr = 0; rr < 4; ++rr) {
          size_t o = (size_t)z * oz + (size_t)(row + rr) * old_ + col;
          float v = acc[i][j][rr] + bb;
          if constexpr (EPI == 2) v += bf2f(addbf[o]);
          out[o] = cvt_bf16(v);
        }
      }
    }
  }
}

// ---------------- setup kernels ----------------

__global__ __launch_bounds__(256) void emb_kernel(const int* __restrict__ labels,
                                                  const float* __restrict__ labW,
                                                  const float* __restrict__ timeW,
                                                  unsigned short* __restrict__ embd) {
  int idx = blockIdx.x * 256 + threadIdx.x;
  int dd = idx & 511;
  int m = idx >> 9;
  int t = m >> 4;
  embd[idx] = cvt_bf16(labW[labels[m] * 512 + dd] + timeW[t * 512 + dd]);
}

__global__ void k_zeropad(unsigned short* a, unsigned short* b, unsigned short* c) {
  int i = blockIdx.x * 256 + threadIdx.x;
  a[i] = 0; b[i] = 0; c[i] = 0;
}

// interleaved Wcat: row 32q+r -> r<16: X row 16q+r ; r>=16: G row 16q+r-16; (C,C,K)->[1024][1536]
__global__ void k_wcat(const float* __restrict__ wx, const float* __restrict__ wg,
                       unsigned short* __restrict__ wcat) {
  int idx = blockIdx.x * 256 + threadIdx.x;  // over L*1024*1536
  int k = idx % 1536;
  int tmp = idx / 1536;
  int orow = tmp & 1023;
  int l = tmp >> 10;
  int tap = k >> 9, c = k & 511;
  int q = orow >> 5, r = orow & 31;
  int srow = q * 16 + (r & 15);
  const float* src = (r < 16) ? wx : wg;
  float v = src[(((size_t)l * 512 + srow) * 512 + c) * 3 + tap];
  wcat[idx] = cvt_bf16(v);
}

__global__ void k_biascat(const float* __restrict__ bx, const float* __restrict__ bg,
                          float* __restrict__ bcat) {
  int idx = blockIdx.x * 256 + threadIdx.x;  // L*1024
  int orow = idx & 1023, l = idx >> 10;
  int q = orow >> 5, r = orow & 31;
  bcat[idx] = (r < 16) ? bx[l * 512 + q * 16 + r] : bg[l * 512 + q * 16 + (r & 15)];
}

__global__ void cast_kernel(const float* __restrict__ src, unsigned short* __restrict__ dst,
                            int n) {
  int i = blockIdx.x * 256 + threadIdx.x;
  if (i < n) dst[i] = cvt_bf16(src[i]);
}

// per-layer 512x512 transpose, fp32 -> bf16
__global__ __launch_bounds__(256) void k_tr512(const float* __restrict__ w,
                                               unsigned short* __restrict__ wt) {
  __shared__ unsigned short t[64][65];
  int r0 = blockIdx.x * 64, c0 = blockIdx.y * 64;
  size_t base = (size_t)blockIdx.z * 512 * 512;
  int c = threadIdx.x & 63, rr = threadIdx.x >> 6;
#pragma unroll
  for (int i = 0; i < 16; ++i) {
    int r = rr + i * 4;
    t[r][c] = cvt_bf16(w[base + (size_t)(r0 + r) * 512 + c0 + c]);
  }
  __syncthreads();
#pragma unroll
  for (int i = 0; i < 16; ++i) {
    int r = rr + i * 4;
    wt[base + (size_t)(c0 + r) * 512 + r0 + c] = t[c][r];
  }
}

__global__ void transposeSmall_kernel(const float* __restrict__ w, float* __restrict__ wt) {
  int idx = blockIdx.x * 256 + threadIdx.x;
  int v = idx >> 9;
  int c = idx & 511;
  wt[c * Vn + v] = w[idx];
}

__global__ void esum_kernel(const float* __restrict__ enc, float* __restrict__ Esum) {
  int p = blockIdx.x * 256 + threadIdx.x;
  float s = 0.f;
  for (int ss = 0; ss < Sn; ++ss) s += enc[(size_t)ss * Bn * En + p];
  Esum[p] = s;
}

// enc (S,B,E) fp32 -> encT (B,E,S) bf16
__global__ __launch_bounds__(256) void k_encT(const float* __restrict__ enc,
                                              unsigned short* __restrict__ encT) {
  __shared__ unsigned short t[64][66];
  int s0 = blockIdx.x * 64, e0 = blockIdx.y * 64, b = blockIdx.z;
  int c = threadIdx.x & 63, r0 = threadIdx.x >> 6;
#pragma unroll
  for (int i = 0; i < 16; ++i) {
    int r = r0 + i * 4;
    t[r][c] = cvt_bf16(enc[((size_t)(s0 + r) * Bn + b) * En + e0 + c]);
  }
  __syncthreads();
#pragma unroll
  for (int i = 0; i < 16; ++i) {
    int r = r0 + i * 4;
    encT[((size_t)b * En + e0 + r) * Sn + s0 + c] = t[c][r];
  }
}

__global__ void k_biasprep(const float* __restrict__ i2e, const float* __restrict__ res_b,
                           const float* __restrict__ in2enc_b, const float* __restrict__ lab2enc_b,
                           const float* __restrict__ e2i_b, const float* __restrict__ inres_b,
                           float* __restrict__ bd, float* __restrict__ bh) {
  int idx = blockIdx.x * 256 + threadIdx.x;  // L*512
  int l = idx >> 9;
  float v = 0.f;
  const float* row = i2e + (size_t)idx * 512;
  const float* rb = res_b + l * 512;
  for (int c = 0; c < 512; ++c) v += row[c] * rb[c];
  bd[idx] = v + in2enc_b[idx] + lab2enc_b[idx];
  bh[idx] = res_b[idx] + e2i_b[idx] + inres_b[idx];
}

// den[row] = d[row] . Esum[b]
__global__ __launch_bounds__(256) void den_kernel(const unsigned short* __restrict__ d,
                                                  const float* __restrict__ Esum,
                                                  float* __restrict__ den) {
  int gtid = blockIdx.x * 256 + threadIdx.x;
  int row = gtid >> 6;
  int lane = threadIdx.x & 63;
  int b = row & 15;
  const unsigned short* dp = d + (size_t)row * 512 + lane * 8;
  const float* ep = Esum + b * 512 + lane * 8;
  float s = 0.f;
#pragma unroll
  for (int q = 0; q < 8; ++q) s += bf2f(dp[q]) * ep[q];
  for (int off = 32; off; off >>= 1) s += __shfl_down(s, off, 64);
  if (lane == 0) den[row] = s;
}

// out = h@opW^T + emb@orW^T + biases (fp32)
__global__ __launch_bounds__(256) void out_kernel(const unsigned short* __restrict__ hd,
                                                  const unsigned short* __restrict__ embd,
                                                  const float* __restrict__ opwT,
                                                  const float* __restrict__ opb,
                                                  const float* __restrict__ orwT,
                                                  const float* __restrict__ orb,
                                                  float* __restrict__ out) {
  __shared__ float rows[8][1024];
  int m0 = blockIdx.x * 8;
  int tid = threadIdx.x;
  for (int i = tid; i < 8 * 512; i += 256) {
    int r = i >> 9, c = i & 511;
    rows[r][c] = bf2f(hd[(size_t)(m0 + r) * 512 + c]);
    rows[r][512 + c] = bf2f(embd[(size_t)(m0 + r) * 512 + c]);
  }
  __syncthreads();
  int r = tid >> 5, v = tid & 31;
  float acc = opb[v] + orb[v];
  for (int c = 0; c < 512; ++c) acc += rows[r][c] * opwT[c * Vn + v];
  for (int c = 0; c < 512; ++c) acc += rows[r][512 + c] * orwT[c * Vn + v];
  out[(size_t)(m0 + r) * Vn + v] = acc;
}

// ---------------- host ----------------

extern "C" void kernel_launch(void* const* d_in, const int* in_sizes, int n_in,
                              void* d_out, int out_size, void* d_ws, size_t ws_size,
                              hipStream_t stream) {
  const int* labels = (const int*)d_in[0];
  const float* enc = (const float*)d_in[1];
  const float* labW = (const float*)d_in[2];
  const float* timeW = (const float*)d_in[3];
  const float* conv_glu_w = (const float*)d_in[4];
  const float* conv_glu_b = (const float*)d_in[5];
  const float* conv_id_w = (const float*)d_in[6];
  const float* conv_id_b = (const float*)d_in[7];
  const float* res_proj_w = (const float*)d_in[8];
  const float* res_proj_b = (const float*)d_in[9];
  const float* inres_w = (const float*)d_in[10];
  const float* inres_b = (const float*)d_in[11];
  const float* in2enc_w = (const float*)d_in[12];
  const float* in2enc_b = (const float*)d_in[13];
  const float* lab2enc_w = (const float*)d_in[14];
  const float* lab2enc_b = (const float*)d_in[15];
  const float* enc2in_w = (const float*)d_in[16];
  const float* enc2in_b = (const float*)d_in[17];
  const float* out_res_w = (const float*)d_in[18];
  const float* out_res_b = (const float*)d_in[19];
  const float* out_proj_w = (const float*)d_in[20];
  const float* out_proj_b = (const float*)d_in[21];
  float* out = (float*)d_out;

  char* cur = (char*)d_ws;
  auto alloc = [&](size_t bytes) {
    char* p = cur;
    cur += (bytes + 255) & ~(size_t)255;
    return p;
  };
  const size_t BIG = (size_t)MROWS * 512;
  const size_t WN = (size_t)Ln * Cn * Cn;
  const size_t ZL = (size_t)512 * 512;  // per-layer / per-b matrix stride
  float* den = (float*)alloc(MROWS * 4);
  float* EsumB = (float*)alloc(Bn * En * 4);
  float* opwT = (float*)alloc(Cn * Vn * 4);
  float* orwT = (float*)alloc(Cn * Vn * 4);
  float* bd = (float*)alloc(Ln * 512 * 4);
  float* bh = (float*)alloc(Ln * 512 * 4);
  float* bcat = (float*)alloc(Ln * 1024 * 4);
  unsigned short* embp = (unsigned short*)alloc((PADE + BIG) * 2);
  unsigned short* h0p = (unsigned short*)alloc((PADE + BIG) * 2);
  unsigned short* h1p = (unsigned short*)alloc((PADE + BIG) * 2);
  unsigned short* glubf = (unsigned short*)alloc(BIG * 2);
  unsigned short* dbf = (unsigned short*)alloc(BIG * 2);
  unsigned short* ctxbf = (unsigned short*)alloc(BIG * 2);
  unsigned short* encT = (unsigned short*)alloc((size_t)Bn * En * Sn * 2);
  unsigned short* Mbf = (unsigned short*)alloc((size_t)Bn * En * En * 2);
  unsigned short* wres = (unsigned short*)alloc(WN * 2);
  unsigned short* resT = (unsigned short*)alloc(WN * 2);
  unsigned short* wfuse = (unsigned short*)alloc(WN * 2);
  unsigned short* wcat = (unsigned short*)alloc((size_t)Ln * 1024 * 1536 * 2);
  unsigned short* w_i2e = (unsigned short*)alloc(WN * 2);
  unsigned short* w_l2e = (unsigned short*)alloc(WN * 2);
  unsigned short* w_inr = (unsigned short*)alloc(WN * 2);
  unsigned short* w_e2i = (unsigned short*)alloc(WN * 2);

  unsigned short* embd = embp + PADE;
  unsigned short* h0d = h0p + PADE;
  unsigned short* h1d = h1p + PADE;

  // setup
  emb_kernel<<<MROWS * 512 / 256, 256, 0, stream>>>(labels, labW, timeW, embd);
  k_zeropad<<<PADE / 256, 256, 0, stream>>>(embp, h0p, h1p);
  k_wcat<<<Ln * 1024 * 1536 / 256, 256, 0, stream>>>(conv_glu_w, conv_id_w, wcat);
  k_biascat<<<Ln * 1024 / 256, 256, 0, stream>>>(conv_glu_b, conv_id_b, bcat);
  cast_kernel<<<WN / 256, 256, 0, stream>>>(res_proj_w, wres, WN);
  cast_kernel<<<WN / 256, 256, 0, stream>>>(in2enc_w, w_i2e, WN);
  cast_kernel<<<WN / 256, 256, 0, stream>>>(lab2enc_w, w_l2e, WN);
  cast_kernel<<<WN / 256, 256, 0, stream>>>(inres_w, w_inr, WN);
  cast_kernel<<<WN / 256, 256, 0, stream>>>(enc2in_w, w_e2i, WN);
  k_tr512<<<dim3(8, 8, Ln), 256, 0, stream>>>(res_proj_w, resT);
  k_biasprep<<<Ln * 512 / 256, 256, 0, stream>>>(in2enc_w, res_proj_b, in2enc_b, lab2enc_b,
                                                 enc2in_b, inres_b, bd, bh);
  transposeSmall_kernel<<<Vn * Cn / 256, 256, 0, stream>>>(out_proj_w, opwT);
  transposeSmall_kernel<<<Vn * Cn / 256, 256, 0, stream>>>(out_res_w, orwT);
  esum_kernel<<<Bn * En / 256, 256, 0, stream>>>(enc, EsumB);
  k_encT<<<dim3(Sn / 64, En / 64, Bn), 256, 0, stream>>>(enc, encT);
  // gram: M[b] = encT[b] @ encT[b]^T
  g2<4, 8><<<dim3(4, 4, Bn), 512, 0, stream>>>(encT, encT, encT, Sn, ZL, encT, encT, encT, Sn,
                                               ZL, nullptr, nullptr, nullptr, Mbf, 512, ZL);
  // wfuse: W'[l] = i2e[l] @ resT[l]
  g2<4, 8><<<dim3(4, 4, Ln), 512, 0, stream>>>(w_i2e, w_i2e, w_i2e, 512, ZL, resT, resT, resT,
                                               512, ZL, nullptr, nullptr, nullptr, wfuse, 512, ZL);

  const unsigned short* hdata = embd;
  unsigned short* hbufs[2] = {h0d, h1d};
  for (int l = 0; l < Ln; ++l) {
    const size_t wo = (size_t)l * Cn * Cn;
    const unsigned short* wc = wcat + (size_t)l * 1024 * 1536;
    // glu = (h*Wx+bx)*sigmoid(h*Wg+bg), causal taps as 3 K-segments of shifted h
    g2<0, 24><<<dim3(128, 8), 512, 0, stream>>>(
        hdata - 2 * Bn * 512, hdata - Bn * 512, hdata, 512, 0, wc, wc + 512, wc + 1024, 1536, 0,
        bcat + l * 1024, nullptr, nullptr, glubf, 512, 0);
    // d = glu@i2e + h@W' + emb@l2e + bd
    g2<1, 24><<<dim3(128, 4), 512, 0, stream>>>(
        glubf, hdata, embd, 512, 0, w_i2e + wo, wfuse + wo, w_l2e + wo, 512, 0, bd + l * 512,
        nullptr, nullptr, dbf, 512, 0);
    den_kernel<<<MROWS / 4, 256, 0, stream>>>(dbf, EsumB, den);
    // ctx = (d @ M[b]) / den
    g2<3, 8><<<dim3(8, 4, Bn), 512, 0, stream>>>(dbf, dbf, dbf, 8192, 512, Mbf, Mbf, Mbf, 512,
                                                 ZL, nullptr, nullptr, den, ctxbf, 8192, 512);
    // h_out = h@res^T + ctx@e2i + emb@inres + bh + glu
    g2<2, 24><<<dim3(128, 4), 512, 0, stream>>>(
        hdata, ctxbf, embd, 512, 0, wres + wo, w_e2i + wo, w_inr + wo, 512, 0, bh + l * 512,
        glubf, nullptr, hbufs[l & 1], 512, 0);
    hdata = hbufs[l & 1];
  }

  out_kernel<<<MROWS / 8, 256, 0, stream>>>(hdata, embd, opwT, out_proj_b, orwT, out_res_b, out);
}

// Round 7
// 669.388 us; speedup vs baseline: 8.2589x; 1.0904x over previous
//
#include <hip/hip_runtime.h>
#include <math.h>

#define Tn 1024
#define Bn 16
#define Sn 512
#define Vn 32
#define Cn 512
#define En 512
#define Ln 4
#define Kw 3
#define MROWS 16384
#define PADROWS 32
#define PADE (PADROWS * Cn)

typedef short bf16x8 __attribute__((ext_vector_type(8)));
typedef float f32x4 __attribute__((ext_vector_type(4)));

__device__ __forceinline__ unsigned short cvt_bf16(float x) {
  unsigned u = __builtin_bit_cast(unsigned, x);
  u = (u + 0x7FFFu + ((u >> 16) & 1u)) >> 16;
  return (unsigned short)u;
}
__device__ __forceinline__ float bf2f(unsigned short h) {
  unsigned u = ((unsigned)h) << 16;
  return __builtin_bit_cast(float, u);
}

#define GL16(g, l)                                                                     \
  __builtin_amdgcn_global_load_lds((const __attribute__((address_space(1))) void*)(g), \
                                   (__attribute__((address_space(3))) void*)(l), 16, 0, 0)

template <int N>
__device__ __forceinline__ void wait_vm_bar() {
  asm volatile("s_waitcnt vmcnt(%0)\n\ts_barrier" ::"i"(N) : "memory");
}
__device__ __forceinline__ void tail_bar() {
  asm volatile("s_waitcnt lgkmcnt(0)\n\ts_barrier" ::: "memory");
}

__device__ __forceinline__ const unsigned short* seg_sel(const unsigned short* s0,
                                                         const unsigned short* s1,
                                                         const unsigned short* s2, int q) {
  const unsigned short* r = s0;
  r = (q == 1) ? s1 : r;
  r = (q == 2) ? s2 : r;
  return r;
}

// ---------------- unified 128x128 BK=64 pipelined MFMA GEMM ----------------
// EPI: 0 glu-pair (interleaved Wcat, out 512 cols)
//      1 bias + bf16      2 bias + addbf + bf16      3 ctx (div den)      4 plain bf16
template <int EPI, int NKT>
__global__ __launch_bounds__(512, 4) void g2(
    const unsigned short* __restrict__ a0, const unsigned short* __restrict__ a1,
    const unsigned short* __restrict__ a2, int ald, size_t az,
    const unsigned short* __restrict__ b0, const unsigned short* __restrict__ b1,
    const unsigned short* __restrict__ b2, int bld, size_t bz,
    const float* __restrict__ bias, const unsigned short* __restrict__ addbf,
    const float* __restrict__ dden, unsigned short* __restrict__ out, int old_, size_t oz) {
  __shared__ char SA[32768], SB[32768];
  const int tid = threadIdx.x;
  const int lane = tid & 63, wave = tid >> 6;
  const int r15 = lane & 15;
  const int sq = ((lane >> 4) ^ ((r15 >> 1) & 3)) << 4;
  const int waveM = (wave >> 2) << 6;  // 0 / 64
  const int waveN = (wave & 3) << 5;   // 0..96
  const int m0 = blockIdx.x * 128, n0 = blockIdx.y * 128;
  const int z = blockIdx.z;
  const unsigned short* A0 = a0 + (size_t)z * az;
  const unsigned short* A1 = a1 + (size_t)z * az;
  const unsigned short* A2 = a2 + (size_t)z * az;
  const unsigned short* B0 = b0 + (size_t)z * bz;
  const unsigned short* B1 = b1 + (size_t)z * bz;
  const unsigned short* B2 = b2 + (size_t)z * bz;
  const int strow = tid >> 2;
  const int stcol = ((tid & 3) ^ ((tid >> 3) & 3)) << 3;
  const int lofs = tid * 16;
  f32x4 acc[4][2] = {};

#define STAGE_T(KT, SL)                                                                  \
  do {                                                                                   \
    const unsigned short* ab_ = seg_sel(A0, A1, A2, (KT) >> 3) +                         \
                                (size_t)(m0 + strow) * ald + (((KT) & 7) << 6) + stcol;  \
    const unsigned short* bb_ = seg_sel(B0, B1, B2, (KT) >> 3) +                         \
                                (size_t)(n0 + strow) * bld + (((KT) & 7) << 6) + stcol;  \
    GL16(ab_, SA + (SL) * 16384 + lofs);                                                 \
    GL16(ab_ + 32, SA + (SL) * 16384 + 8192 + lofs);                                     \
    GL16(bb_, SB + (SL) * 16384 + lofs);                                                 \
    GL16(bb_ + 32, SB + (SL) * 16384 + 8192 + lofs);                                     \
  } while (0)

  STAGE_T(0, 0);
  for (int kt = 0; kt < NKT; ++kt) {
    const int sl = kt & 1;
    if (kt + 1 < NKT) {
      STAGE_T(kt + 1, sl ^ 1);
      wait_vm_bar<4>();
    } else {
      wait_vm_bar<0>();
    }
    const char* abase = SA + sl * 16384 + (waveM + r15) * 64 + sq;
    const char* bbase = SB + sl * 16384 + (waveN + r15) * 64 + sq;
    __builtin_amdgcn_s_setprio(1);
#pragma unroll
    for (int kp = 0; kp < 2; ++kp) {
      bf16x8 af[4], bfv[2];
#pragma unroll
      for (int i = 0; i < 4; ++i) af[i] = *(const bf16x8*)(abase + kp * 8192 + i * 1024);
#pragma unroll
      for (int j = 0; j < 2; ++j) bfv[j] = *(const bf16x8*)(bbase + kp * 8192 + j * 1024);
#pragma unroll
      for (int i = 0; i < 4; ++i)
#pragma unroll
        for (int j = 0; j < 2; ++j)
          acc[i][j] = __builtin_amdgcn_mfma_f32_16x16x32_bf16(af[i], bfv[j], acc[i][j], 0, 0, 0);
    }
    __builtin_amdgcn_s_setprio(0);
    tail_bar();
  }
#undef STAGE_T

  const int q4 = (lane >> 4) << 2;
#pragma unroll
  for (int i = 0; i < 4; ++i) {
    int row = m0 + waveM + i * 16 + q4;
    if constexpr (EPI == 0) {
      int xcol = ((n0 + waveN) >> 1) + r15;
      float bx = bias[n0 + waveN + r15];
      float bg = bias[n0 + waveN + 16 + r15];
#pragma unroll
      for (int rr = 0; rr < 4; ++rr) {
        float xv = acc[i][0][rr] + bx;
        float gv = acc[i][1][rr] + bg;
        float sg = 1.f / (1.f + __expf(-gv));
        out[(size_t)(row + rr) * 512 + xcol] = cvt_bf16(xv * sg);
      }
    } else if constexpr (EPI == 3) {
#pragma unroll
      for (int rr = 0; rr < 4; ++rr) {
        float inv = 1.f / dden[z + (size_t)(row + rr) * 16];
#pragma unroll
        for (int j = 0; j < 2; ++j) {
          int col = n0 + waveN + j * 16 + r15;
          out[(size_t)z * oz + (size_t)(row + rr) * old_ + col] = cvt_bf16(acc[i][j][rr] * inv);
        }
      }
    } else {
#pragma unroll
      for (int j = 0; j < 2; ++j) {
        int col = n0 + waveN + j * 16 + r15;
        float bb = (EPI == 4) ? 0.f : bias[col];
#pragma unroll
        for (int rr = 0; rr < 4; ++rr) {
          size_t o = (size_t)z * oz + (size_t)(row + rr) * old_ + col;
          float v = acc[i][j][rr] + bb;
          if constexpr (EPI == 2) v += bf2f(addbf[o]);
          out[o] = cvt_bf16(v);
        }
      }
    }
  }
}

// ---------------- MFMA output projection: out(fp32) = [h emb] @ Wcat2^T + bcat2 ----------------
// M=16384, N=32, K=1024 (k<512: h, k>=512: emb). 256 threads, 4 waves, wave = 32 rows x 32 cols.
__global__ __launch_bounds__(256, 4) void k_outm(const unsigned short* __restrict__ hd,
                                                 const unsigned short* __restrict__ embd,
                                                 const unsigned short* __restrict__ wcat2,
                                                 const float* __restrict__ bcat2,
                                                 float* __restrict__ out) {
  __shared__ char SA[32768];  // 2 slots x (128 rows x 64B) x 2 halves
  __shared__ char SBo[8192];  // 2 slots x (32 rows x 64B) x 2 halves
  const int tid = threadIdx.x;
  const int lane = tid & 63, wave = tid >> 6;
  const int r15 = lane & 15;
  const int sq = ((lane >> 4) ^ ((r15 >> 1) & 3)) << 4;
  const int waveM = wave << 5;  // 0,32,64,96
  const int m0 = blockIdx.x * 128;
  f32x4 acc[2][2] = {};
  // A staging map: issue q in 0..3 -> unit = (q&1)*256+tid covers half (q>>1)
  const int aru = ((tid & 255) + 0);  // placeholder, rows via units below
  (void)aru;

#define OSTAGE(KT, SL)                                                                         \
  do {                                                                                         \
    const unsigned short* aseg = ((KT) < 8) ? hd : embd;                                       \
    int kc = ((KT) & 7) << 6;                                                                  \
    _Pragma("unroll") for (int q = 0; q < 2; ++q) {                                            \
      int unit = q * 256 + tid;                                                                \
      int row = unit >> 2, chunk = unit & 3;                                                   \
      int swc = chunk ^ ((row >> 1) & 3);                                                      \
      GL16(aseg + (size_t)(m0 + row) * 512 + kc + swc * 8, SA + (SL) * 16384 + unit * 16);     \
      GL16(aseg + (size_t)(m0 + row) * 512 + kc + 32 + swc * 8,                                \
           SA + (SL) * 16384 + 8192 + unit * 16);                                              \
    }                                                                                          \
    {                                                                                          \
      int half = tid >> 7;                                                                     \
      int u = tid & 127;                                                                       \
      int row = u >> 2, chunk = u & 3;                                                         \
      int swc = chunk ^ ((row >> 1) & 3);                                                      \
      GL16(wcat2 + (size_t)row * 1024 + ((KT) << 6) + half * 32 + swc * 8,                     \
           SBo + (SL) * 4096 + half * 2048 + u * 16);                                          \
    }                                                                                          \
  } while (0)

  OSTAGE(0, 0);
  for (int kt = 0; kt < 16; ++kt) {
    const int sl = kt & 1;
    if (kt + 1 < 16) {
      OSTAGE(kt + 1, sl ^ 1);
      wait_vm_bar<5>();
    } else {
      wait_vm_bar<0>();
    }
    const char* abase = SA + sl * 16384 + (waveM + r15) * 64 + sq;
    const char* bbase = SBo + sl * 4096 + r15 * 64 + sq;
    __builtin_amdgcn_s_setprio(1);
#pragma unroll
    for (int kp = 0; kp < 2; ++kp) {
      bf16x8 af[2], bfv[2];
#pragma unroll
      for (int i = 0; i < 2; ++i) af[i] = *(const bf16x8*)(abase + kp * 8192 + i * 1024);
#pragma unroll
      for (int j = 0; j < 2; ++j) bfv[j] = *(const bf16x8*)(bbase + kp * 2048 + j * 1024);
#pragma unroll
      for (int i = 0; i < 2; ++i)
#pragma unroll
        for (int j = 0; j < 2; ++j)
          acc[i][j] = __builtin_amdgcn_mfma_f32_16x16x32_bf16(af[i], bfv[j], acc[i][j], 0, 0, 0);
    }
    __builtin_amdgcn_s_setprio(0);
    tail_bar();
  }
#undef OSTAGE

  const int q4 = (lane >> 4) << 2;
#pragma unroll
  for (int i = 0; i < 2; ++i) {
    int row = m0 + waveM + i * 16 + q4;
#pragma unroll
    for (int j = 0; j < 2; ++j) {
      int col = j * 16 + r15;
      float bb = bcat2[col];
#pragma unroll
      for (int rr = 0; rr < 4; ++rr)
        out[(size_t)(row + rr) * 32 + col] = acc[i][j][rr] + bb;
    }
  }
}

// ---------------- setup kernels ----------------

__global__ __launch_bounds__(256) void emb_kernel(const int* __restrict__ labels,
                                                  const float* __restrict__ labW,
                                                  const float* __restrict__ timeW,
                                                  unsigned short* __restrict__ embd) {
  int idx = blockIdx.x * 256 + threadIdx.x;
  int dd = idx & 511;
  int m = idx >> 9;
  int t = m >> 4;
  embd[idx] = cvt_bf16(labW[labels[m] * 512 + dd] + timeW[t * 512 + dd]);
}

__global__ void k_zeropad(unsigned short* a, unsigned short* b, unsigned short* c) {
  int i = blockIdx.x * 256 + threadIdx.x;
  a[i] = 0; b[i] = 0; c[i] = 0;
}

// interleaved Wcat: row 32q+r -> r<16: X row 16q+r ; r>=16: G row 16q+r-16; (C,C,K)->[1024][1536]
__global__ void k_wcat(const float* __restrict__ wx, const float* __restrict__ wg,
                       unsigned short* __restrict__ wcat) {
  int idx = blockIdx.x * 256 + threadIdx.x;  // over L*1024*1536
  int k = idx % 1536;
  int tmp = idx / 1536;
  int orow = tmp & 1023;
  int l = tmp >> 10;
  int tap = k >> 9, c = k & 511;
  int q = orow >> 5, r = orow & 31;
  int srow = q * 16 + (r & 15);
  const float* src = (r < 16) ? wx : wg;
  float v = src[(((size_t)l * 512 + srow) * 512 + c) * 3 + tap];
  wcat[idx] = cvt_bf16(v);
}

__global__ void k_biascat(const float* __restrict__ bx, const float* __restrict__ bg,
                          float* __restrict__ bcat) {
  int idx = blockIdx.x * 256 + threadIdx.x;  // L*1024
  int orow = idx & 1023, l = idx >> 10;
  int q = orow >> 5, r = orow & 31;
  bcat[idx] = (r < 16) ? bx[l * 512 + q * 16 + r] : bg[l * 512 + q * 16 + (r & 15)];
}

// Wcat2[32][1024]: k<512 -> out_proj_w, k>=512 -> out_res_w; also bcat2[v]
__global__ void k_wcat2(const float* __restrict__ opw, const float* __restrict__ orw,
                        const float* __restrict__ opb, const float* __restrict__ orb,
                        unsigned short* __restrict__ wcat2, float* __restrict__ bcat2) {
  int idx = blockIdx.x * 256 + threadIdx.x;  // 32*1024
  int v = idx >> 10, k = idx & 1023;
  float val = (k < 512) ? opw[v * 512 + k] : orw[v * 512 + k - 512];
  wcat2[idx] = cvt_bf16(val);
  if (idx < 32) bcat2[idx] = opb[idx] + orb[idx];
}

__global__ void cast_kernel(const float* __restrict__ src, unsigned short* __restrict__ dst,
                            int n) {
  int i = blockIdx.x * 256 + threadIdx.x;
  if (i < n) dst[i] = cvt_bf16(src[i]);
}

// per-layer 512x512 transpose, fp32 -> bf16
__global__ __launch_bounds__(256) void k_tr512(const float* __restrict__ w,
                                               unsigned short* __restrict__ wt) {
  __shared__ unsigned short t[64][65];
  int r0 = blockIdx.x * 64, c0 = blockIdx.y * 64;
  size_t base = (size_t)blockIdx.z * 512 * 512;
  int c = threadIdx.x & 63, rr = threadIdx.x >> 6;
#pragma unroll
  for (int i = 0; i < 16; ++i) {
    int r = rr + i * 4;
    t[r][c] = cvt_bf16(w[base + (size_t)(r0 + r) * 512 + c0 + c]);
  }
  __syncthreads();
#pragma unroll
  for (int i = 0; i < 16; ++i) {
    int r = rr + i * 4;
    wt[base + (size_t)(c0 + r) * 512 + r0 + c] = t[c][r];
  }
}

__global__ void esum_kernel(const float* __restrict__ enc, float* __restrict__ Esum) {
  int p = blockIdx.x * 256 + threadIdx.x;
  float s = 0.f;
  for (int ss = 0; ss < Sn; ++ss) s += enc[(size_t)ss * Bn * En + p];
  Esum[p] = s;
}

// enc (S,B,E) fp32 -> encT (B,E,S) bf16
__global__ __launch_bounds__(256) void k_encT(const float* __restrict__ enc,
                                              unsigned short* __restrict__ encT) {
  __shared__ unsigned short t[64][66];
  int s0 = blockIdx.x * 64, e0 = blockIdx.y * 64, b = blockIdx.z;
  int c = threadIdx.x & 63, r0 = threadIdx.x >> 6;
#pragma unroll
  for (int i = 0; i < 16; ++i) {
    int r = r0 + i * 4;
    t[r][c] = cvt_bf16(enc[((size_t)(s0 + r) * Bn + b) * En + e0 + c]);
  }
  __syncthreads();
#pragma unroll
  for (int i = 0; i < 16; ++i) {
    int r = r0 + i * 4;
    encT[((size_t)b * En + e0 + r) * Sn + s0 + c] = t[c][r];
  }
}

__global__ void k_biasprep(const float* __restrict__ i2e, const float* __restrict__ res_b,
                           const float* __restrict__ in2enc_b, const float* __restrict__ lab2enc_b,
                           const float* __restrict__ e2i_b, const float* __restrict__ inres_b,
                           float* __restrict__ bd, float* __restrict__ bh) {
  int idx = blockIdx.x * 256 + threadIdx.x;  // L*512
  int l = idx >> 9;
  float v = 0.f;
  const float* row = i2e + (size_t)idx * 512;
  const float* rb = res_b + l * 512;
  for (int c = 0; c < 512; ++c) v += row[c] * rb[c];
  bd[idx] = v + in2enc_b[idx] + lab2enc_b[idx];
  bh[idx] = res_b[idx] + e2i_b[idx] + inres_b[idx];
}

// den[row] = d[row] . Esum[b]
__global__ __launch_bounds__(256) void den_kernel(const unsigned short* __restrict__ d,
                                                  const float* __restrict__ Esum,
                                                  float* __restrict__ den) {
  int gtid = blockIdx.x * 256 + threadIdx.x;
  int row = gtid >> 6;
  int lane = threadIdx.x & 63;
  int b = row & 15;
  const unsigned short* dp = d + (size_t)row * 512 + lane * 8;
  const float* ep = Esum + b * 512 + lane * 8;
  float s = 0.f;
#pragma unroll
  for (int q = 0; q < 8; ++q) s += bf2f(dp[q]) * ep[q];
  for (int off = 32; off; off >>= 1) s += __shfl_down(s, off, 64);
  if (lane == 0) den[row] = s;
}

// ---------------- host ----------------

extern "C" void kernel_launch(void* const* d_in, const int* in_sizes, int n_in,
                              void* d_out, int out_size, void* d_ws, size_t ws_size,
                              hipStream_t stream) {
  const int* labels = (const int*)d_in[0];
  const float* enc = (const float*)d_in[1];
  const float* labW = (const float*)d_in[2];
  const float* timeW = (const float*)d_in[3];
  const float* conv_glu_w = (const float*)d_in[4];
  const float* conv_glu_b = (const float*)d_in[5];
  const float* conv_id_w = (const float*)d_in[6];
  const float* conv_id_b = (const float*)d_in[7];
  const float* res_proj_w = (const float*)d_in[8];
  const float* res_proj_b = (const float*)d_in[9];
  const float* inres_w = (const float*)d_in[10];
  const float* inres_b = (const float*)d_in[11];
  const float* in2enc_w = (const float*)d_in[12];
  const float* in2enc_b = (const float*)d_in[13];
  const float* lab2enc_w = (const float*)d_in[14];
  const float* lab2enc_b = (const float*)d_in[15];
  const float* enc2in_w = (const float*)d_in[16];
  const float* enc2in_b = (const float*)d_in[17];
  const float* out_res_w = (const float*)d_in[18];
  const float* out_res_b = (const float*)d_in[19];
  const float* out_proj_w = (const float*)d_in[20];
  const float* out_proj_b = (const float*)d_in[21];
  float* out = (float*)d_out;

  char* cur = (char*)d_ws;
  auto alloc = [&](size_t bytes) {
    char* p = cur;
    cur += (bytes + 255) & ~(size_t)255;
    return p;
  };
  const size_t BIG = (size_t)MROWS * 512;
  const size_t WN = (size_t)Ln * Cn * Cn;
  const size_t ZL = (size_t)512 * 512;  // per-layer / per-b matrix stride
  float* den = (float*)alloc(MROWS * 4);
  float* EsumB = (float*)alloc(Bn * En * 4);
  float* bd = (float*)alloc(Ln * 512 * 4);
  float* bh = (float*)alloc(Ln * 512 * 4);
  float* bcat = (float*)alloc(Ln * 1024 * 4);
  float* bcat2 = (float*)alloc(32 * 4);
  unsigned short* embp = (unsigned short*)alloc((PADE + BIG) * 2);
  unsigned short* h0p = (unsigned short*)alloc((PADE + BIG) * 2);
  unsigned short* h1p = (unsigned short*)alloc((PADE + BIG) * 2);
  unsigned short* glubf = (unsigned short*)alloc(BIG * 2);
  unsigned short* dbf = (unsigned short*)alloc(BIG * 2);
  unsigned short* ctxbf = (unsigned short*)alloc(BIG * 2);
  unsigned short* encT = (unsigned short*)alloc((size_t)Bn * En * Sn * 2);
  unsigned short* Mbf = (unsigned short*)alloc((size_t)Bn * En * En * 2);
  unsigned short* wres = (unsigned short*)alloc(WN * 2);
  unsigned short* resT = (unsigned short*)alloc(WN * 2);
  unsigned short* wfuse = (unsigned short*)alloc(WN * 2);
  unsigned short* wcat = (unsigned short*)alloc((size_t)Ln * 1024 * 1536 * 2);
  unsigned short* wcat2 = (unsigned short*)alloc((size_t)32 * 1024 * 2);
  unsigned short* w_i2e = (unsigned short*)alloc(WN * 2);
  unsigned short* w_l2e = (unsigned short*)alloc(WN * 2);
  unsigned short* w_inr = (unsigned short*)alloc(WN * 2);
  unsigned short* w_e2i = (unsigned short*)alloc(WN * 2);

  unsigned short* embd = embp + PADE;
  unsigned short* h0d = h0p + PADE;
  unsigned short* h1d = h1p + PADE;

  // setup
  emb_kernel<<<MROWS * 512 / 256, 256, 0, stream>>>(labels, labW, timeW, embd);
  k_zeropad<<<PADE / 256, 256, 0, stream>>>(embp, h0p, h1p);
  k_wcat<<<Ln * 1024 * 1536 / 256, 256, 0, stream>>>(conv_glu_w, conv_id_w, wcat);
  k_biascat<<<Ln * 1024 / 256, 256, 0, stream>>>(conv_glu_b, conv_id_b, bcat);
  k_wcat2<<<32 * 1024 / 256, 256, 0, stream>>>(out_proj_w, out_res_w, out_proj_b, out_res_b,
                                               wcat2, bcat2);
  cast_kernel<<<WN / 256, 256, 0, stream>>>(res_proj_w, wres, WN);
  cast_kernel<<<WN / 256, 256, 0, stream>>>(in2enc_w, w_i2e, WN);
  cast_kernel<<<WN / 256, 256, 0, stream>>>(lab2enc_w, w_l2e, WN);
  cast_kernel<<<WN / 256, 256, 0, stream>>>(inres_w, w_inr, WN);
  cast_kernel<<<WN / 256, 256, 0, stream>>>(enc2in_w, w_e2i, WN);
  k_tr512<<<dim3(8, 8, Ln), 256, 0, stream>>>(res_proj_w, resT);
  k_biasprep<<<Ln * 512 / 256, 256, 0, stream>>>(in2enc_w, res_proj_b, in2enc_b, lab2enc_b,
                                                 enc2in_b, inres_b, bd, bh);
  esum_kernel<<<Bn * En / 256, 256, 0, stream>>>(enc, EsumB);
  k_encT<<<dim3(Sn / 64, En / 64, Bn), 256, 0, stream>>>(enc, encT);
  // gram: M[b] = encT[b] @ encT[b]^T
  g2<4, 8><<<dim3(4, 4, Bn), 512, 0, stream>>>(encT, encT, encT, Sn, ZL, encT, encT, encT, Sn,
                                               ZL, nullptr, nullptr, nullptr, Mbf, 512, ZL);
  // wfuse: W'[l] = i2e[l] @ resT[l]
  g2<4, 8><<<dim3(4, 4, Ln), 512, 0, stream>>>(w_i2e, w_i2e, w_i2e, 512, ZL, resT, resT, resT,
                                               512, ZL, nullptr, nullptr, nullptr, wfuse, 512, ZL);

  const unsigned short* hdata = embd;
  unsigned short* hbufs[2] = {h0d, h1d};
  for (int l = 0; l < Ln; ++l) {
    const size_t wo = (size_t)l * Cn * Cn;
    const unsigned short* wc = wcat + (size_t)l * 1024 * 1536;
    // glu = (h*Wx+bx)*sigmoid(h*Wg+bg), causal taps as 3 K-segments of shifted h
    g2<0, 24><<<dim3(128, 8), 512, 0, stream>>>(
        hdata - 2 * Bn * 512, hdata - Bn * 512, hdata, 512, 0, wc, wc + 512, wc + 1024, 1536, 0,
        bcat + l * 1024, nullptr, nullptr, glubf, 512, 0);
    // d = glu@i2e + h@W' + emb@l2e + bd
    g2<1, 24><<<dim3(128, 4), 512, 0, stream>>>(
        glubf, hdata, embd, 512, 0, w_i2e + wo, wfuse + wo, w_l2e + wo, 512, 0, bd + l * 512,
        nullptr, nullptr, dbf, 512, 0);
    den_kernel<<<MROWS / 4, 256, 0, stream>>>(dbf, EsumB, den);
    // ctx = (d @ M[b]) / den
    g2<3, 8><<<dim3(8, 4, Bn), 512, 0, stream>>>(dbf, dbf, dbf, 8192, 512, Mbf, Mbf, Mbf, 512,
                                                 ZL, nullptr, nullptr, den, ctxbf, 8192, 512);
    // h_out = h@res^T + ctx@e2i + emb@inres + bh + glu
    g2<2, 24><<<dim3(128, 4), 512, 0, stream>>>(
        hdata, ctxbf, embd, 512, 0, wres + wo, w_e2i + wo, w_inr + wo, 512, 0, bh + l * 512,
        glubf, nullptr, hbufs[l & 1], 512, 0);
    hdata = hbufs[l & 1];
  }

  k_outm<<<MROWS / 128, 256, 0, stream>>>(hdata, embd, wcat2, bcat2, out);
}

// Round 8
// 661.000 us; speedup vs baseline: 8.3637x; 1.0127x over previous
//
#include <hip/hip_runtime.h>
#include <math.h>

#define Tn 1024
#define Bn 16
#define Sn 512
#define Vn 32
#define Cn 512
#define En 512
#define Ln 4
#define Kw 3
#define MROWS 16384
#define PADROWS 32
#define PADE (PADROWS * Cn)

typedef short bf16x8 __attribute__((ext_vector_type(8)));
typedef float f32x4 __attribute__((ext_vector_type(4)));

__device__ __forceinline__ unsigned short cvt_bf16(float x) {
  unsigned u = __builtin_bit_cast(unsigned, x);
  u = (u + 0x7FFFu + ((u >> 16) & 1u)) >> 16;
  return (unsigned short)u;
}
__device__ __forceinline__ float bf2f(unsigned short h) {
  unsigned u = ((unsigned)h) << 16;
  return __builtin_bit_cast(float, u);
}

#define GL16(g, l)                                                                     \
  __builtin_amdgcn_global_load_lds((const __attribute__((address_space(1))) void*)(g), \
                                   (__attribute__((address_space(3))) void*)(l), 16, 0, 0)

template <int N>
__device__ __forceinline__ void wait_vm_bar() {
  asm volatile("s_waitcnt vmcnt(%0)\n\ts_barrier" ::"i"(N) : "memory");
}
__device__ __forceinline__ void tail_bar() {
  asm volatile("s_waitcnt lgkmcnt(0)\n\ts_barrier" ::: "memory");
}
#define VMB(N)                                                   \
  do {                                                           \
    asm volatile("s_waitcnt vmcnt(%0)" ::"i"(N) : "memory");     \
    __builtin_amdgcn_s_barrier();                                \
  } while (0)

__device__ __forceinline__ const unsigned short* seg_sel(const unsigned short* s0,
                                                         const unsigned short* s1,
                                                         const unsigned short* s2, int q) {
  const unsigned short* r = s0;
  r = (q == 1) ? s1 : r;
  r = (q == 2) ? s2 : r;
  return r;
}

// ================= g3glu: 256x256, BK=64, deep-phase schedule, GLU epilogue =================
// 8 waves (wm 0-1, wn 0-3); wave owns rows {wm*64..+63, 128+wm*64..+63} x cols {wn*32..+31, 128+wn*32..+31}
// per K-tile: 4 phases (Ah0Bh0 | Bh1 | Ah1 | reuse), stages next kt's halves in consumption order,
// vmcnt(6) at ph1-3 (>=3-phase latency cover), buffers alternate per kt.
__global__ __launch_bounds__(512, 2) void g3glu(const unsigned short* __restrict__ hd,
                                                const unsigned short* __restrict__ wc,
                                                const float* __restrict__ bias,
                                                unsigned short* __restrict__ out) {
  __shared__ char LA[2][32768];
  __shared__ char LB[2][32768];
  const int tid = threadIdx.x;
  const int lane = tid & 63;
  const int wm = (tid >> 6) >> 2;
  const int wn = (tid >> 6) & 3;
  const int r15 = lane & 15;
  const int l4 = lane >> 4;
  const int q4 = l4 << 2;
  const int m0 = blockIdx.x * 256, n0 = blockIdx.y * 256;
  const int srow = tid >> 3;
  const int scol = (((tid & 7) ^ (srow & 7)) << 3);
  const int sdst = tid << 4;
  f32x4 acc[8][4] = {};
  bf16x8 afr[4][2], b01[2][2], b23[2][2];
  const unsigned short* hs0 = hd - 2 * 16 * 512;
  const unsigned short* hs1 = hd - 16 * 512;

#define SGA3(KT, H, BB)                                                                     \
  do {                                                                                      \
    const unsigned short* s_ = seg_sel(hs0, hs1, hd, (KT) >> 3) +                           \
                               (size_t)(m0 + (H) * 128 + srow) * 512 + (((KT)&7) << 6) +    \
                               scol;                                                        \
    GL16(s_, LA[BB] + (H) * 16384 + sdst);                                                  \
    GL16(s_ + (size_t)64 * 512, LA[BB] + (H) * 16384 + 8192 + sdst);                        \
  } while (0)
#define SGB3(KT, H, BB)                                                                     \
  do {                                                                                      \
    const unsigned short* s_ =                                                              \
        wc + (size_t)(n0 + (H) * 128 + srow) * 1536 + ((KT) << 6) + scol;                   \
    GL16(s_, LB[BB] + (H) * 16384 + sdst);                                                  \
    GL16(s_ + (size_t)64 * 1536, LB[BB] + (H) * 16384 + 8192 + sdst);                       \
  } while (0)
#define RDA3(SL, FH)                                                                        \
  do {                                                                                      \
    _Pragma("unroll") for (int f = 0; f < 4; ++f) _Pragma("unroll") for (int kp = 0;        \
                                                                         kp < 2; ++kp) {   \
      int ar = ((FH) << 7) + (wm << 6) + (f << 4) + r15;                                    \
      afr[f][kp] =                                                                          \
          *(const bf16x8*)(LA[SL] + ar * 128 + ((((kp << 2) | l4) ^ (ar & 7)) << 4));       \
    }                                                                                       \
  } while (0)
#define RDB3(SL, CH, DST)                                                                   \
  do {                                                                                      \
    _Pragma("unroll") for (int c = 0; c < 2; ++c) _Pragma("unroll") for (int kp = 0;        \
                                                                         kp < 2; ++kp) {   \
      int br = ((CH) << 7) + (wn << 5) + (c << 4) + r15;                                    \
      DST[c][kp] =                                                                          \
          *(const bf16x8*)(LB[SL] + br * 128 + ((((kp << 2) | l4) ^ (br & 7)) << 4));       \
    }                                                                                       \
  } while (0)
#define MM3(BF, F0, C0)                                                                     \
  do {                                                                                      \
    __builtin_amdgcn_s_setprio(1);                                                          \
    _Pragma("unroll") for (int f = 0; f < 4; ++f) _Pragma("unroll") for (int c = 0; c < 2;  \
                                                                         ++c)              \
        _Pragma("unroll") for (int kp = 0; kp < 2; ++kp) acc[(F0) + f][(C0) + c] =          \
            __builtin_amdgcn_mfma_f32_16x16x32_bf16(afr[f][kp], BF[c][kp],                  \
                                                    acc[(F0) + f][(C0) + c], 0, 0, 0);      \
    __builtin_amdgcn_s_setprio(0);                                                          \
  } while (0)
#define GRP3(KT, W1, W2, W3, STG)                                                           \
  do {                                                                                      \
    const int sl_ = (KT)&1, sn_ = sl_ ^ 1;                                                  \
    if (STG) SGA3((KT) + 1, 0, sn_);                                                        \
    VMB(W1);                                                                                \
    RDA3(sl_, 0);                                                                           \
    RDB3(sl_, 0, b01);                                                                      \
    MM3(b01, 0, 0);                                                                         \
    if (STG) SGB3((KT) + 1, 0, sn_);                                                        \
    VMB(W2);                                                                                \
    RDB3(sl_, 1, b23);                                                                      \
    MM3(b23, 0, 2);                                                                         \
    if (STG) SGB3((KT) + 1, 1, sn_);                                                        \
    VMB(W3);                                                                                \
    RDA3(sl_, 1);                                                                           \
    MM3(b23, 4, 2);                                                                         \
    if (STG) SGA3((KT) + 1, 1, sn_);                                                        \
    MM3(b01, 4, 0);                                                                         \
  } while (0)

  // prologue: kt0 halves in consumption order
  SGA3(0, 0, 0);
  SGB3(0, 0, 0);
  SGB3(0, 1, 0);
  SGA3(0, 1, 0);
  for (int kt = 0; kt < 23; ++kt) GRP3(kt, 6, 6, 6, 1);
  GRP3(23, 4, 2, 0, 0);
#undef GRP3

  // epilogue: X/G pairs (c even = X, c odd = G)
#pragma unroll
  for (int f = 0; f < 8; ++f) {
    int grow = m0 + ((f >> 2) << 7) + (wm << 6) + ((f & 3) << 4) + q4;
#pragma unroll
    for (int p = 0; p < 2; ++p) {
      int bcol = n0 + (p << 7) + (wn << 5);
      float bx = bias[bcol + r15];
      float bg = bias[bcol + 16 + r15];
      int xcol = (bcol >> 1) + r15;
#pragma unroll
      for (int rr = 0; rr < 4; ++rr) {
        float xv = acc[f][2 * p][rr] + bx;
        float gv = acc[f][2 * p + 1][rr] + bg;
        float sg = 1.f / (1.f + __expf(-gv));
        out[(size_t)(grow + rr) * 512 + xcol] = cvt_bf16(xv * sg);
      }
    }
  }
}

// ================= g3t: 256x128, BK=64, 2-phase/kt, triple-K-segment GEMM =================
// 8 waves (wm 0-3, wn 0-1); wave rows {wm*32..+31, 128+wm*32..+31}, cols {wn*32..+31, 64+wn*32..+31}
// EPI 1: bias + bf16 out ; EPI 2: bias + addbf + bf16 out
template <int EPI>
__global__ __launch_bounds__(512, 2) void g3t(
    const unsigned short* __restrict__ a0, const unsigned short* __restrict__ a1,
    const unsigned short* __restrict__ a2, const unsigned short* __restrict__ b0,
    const unsigned short* __restrict__ b1, const unsigned short* __restrict__ b2,
    const float* __restrict__ bias, const unsigned short* __restrict__ addbf,
    unsigned short* __restrict__ out) {
  __shared__ char LA[2][32768];
  __shared__ char LB[2][16384];
  const int tid = threadIdx.x;
  const int lane = tid & 63;
  const int wm = (tid >> 6) >> 1;
  const int wn = (tid >> 6) & 1;
  const int r15 = lane & 15;
  const int l4 = lane >> 4;
  const int q4 = l4 << 2;
  const int m0 = blockIdx.x * 256, n0 = blockIdx.y * 128;
  const int srow = tid >> 3;
  const int scol = (((tid & 7) ^ (srow & 7)) << 3);
  const int sdst = tid << 4;
  f32x4 acc[4][4] = {};
  bf16x8 afr[4][2], b01[2][2], b23[2][2];

#define TGA(KT, BB)                                                                         \
  do {                                                                                      \
    const unsigned short* s_ = seg_sel(a0, a1, a2, (KT) >> 3) +                             \
                               (size_t)(m0 + srow) * 512 + (((KT)&7) << 6) + scol;          \
    GL16(s_, LA[BB] + sdst);                                                                \
    GL16(s_ + (size_t)64 * 512, LA[BB] + 8192 + sdst);                                      \
    GL16(s_ + (size_t)128 * 512, LA[BB] + 16384 + sdst);                                    \
    GL16(s_ + (size_t)192 * 512, LA[BB] + 24576 + sdst);                                    \
  } while (0)
#define TGB(KT, BB)                                                                         \
  do {                                                                                      \
    const unsigned short* s_ = seg_sel(b0, b1, b2, (KT) >> 3) +                             \
                               (size_t)(n0 + srow) * 512 + (((KT)&7) << 6) + scol;          \
    GL16(s_, LB[BB] + sdst);                                                                \
    GL16(s_ + (size_t)64 * 512, LB[BB] + 8192 + sdst);                                      \
  } while (0)
#define TRA(SL)                                                                             \
  do {                                                                                      \
    _Pragma("unroll") for (int f = 0; f < 4; ++f) _Pragma("unroll") for (int kp = 0;        \
                                                                         kp < 2; ++kp) {   \
      int ar = ((f >> 1) << 7) + (wm << 5) + ((f & 1) << 4) + r15;                          \
      afr[f][kp] =                                                                          \
          *(const bf16x8*)(LA[SL] + ar * 128 + ((((kp << 2) | l4) ^ (ar & 7)) << 4));       \
    }                                                                                       \
  } while (0)
#define TRB(SL, CH, DST)                                                                    \
  do {                                                                                      \
    _Pragma("unroll") for (int c = 0; c < 2; ++c) _Pragma("unroll") for (int kp = 0;        \
                                                                         kp < 2; ++kp) {   \
      int br = ((CH) << 6) + (wn << 5) + (c << 4) + r15;                                    \
      DST[c][kp] =                                                                          \
          *(const bf16x8*)(LB[SL] + br * 128 + ((((kp << 2) | l4) ^ (br & 7)) << 4));       \
    }                                                                                       \
  } while (0)
#define MMT(BF, C0)                                                                         \
  do {                                                                                      \
    __builtin_amdgcn_s_setprio(1);                                                          \
    _Pragma("unroll") for (int f = 0; f < 4; ++f) _Pragma("unroll") for (int c = 0; c < 2;  \
                                                                         ++c)              \
        _Pragma("unroll") for (int kp = 0; kp < 2; ++kp) acc[f][(C0) + c] =                 \
            __builtin_amdgcn_mfma_f32_16x16x32_bf16(afr[f][kp], BF[c][kp],                  \
                                                    acc[f][(C0) + c], 0, 0, 0);             \
    __builtin_amdgcn_s_setprio(0);                                                          \
  } while (0)
#define TGRP(KT, W1, W2, STG)                                                               \
  do {                                                                                      \
    const int sl_ = (KT)&1, sn_ = sl_ ^ 1;                                                  \
    if (STG) TGA((KT) + 1, sn_);                                                            \
    VMB(W1);                                                                                \
    TRA(sl_);                                                                               \
    TRB(sl_, 0, b01);                                                                       \
    MMT(b01, 0);                                                                            \
    if (STG) TGB((KT) + 1, sn_);                                                            \
    VMB(W2);                                                                                \
    TRB(sl_, 1, b23);                                                                       \
    MMT(b23, 2);                                                                            \
  } while (0)

  TGA(0, 0);
  TGB(0, 0);
  for (int kt = 0; kt < 23; ++kt) TGRP(kt, 5, 6, 1);
  TGRP(23, 1, 0, 0);
#undef TGRP

#pragma unroll
  for (int f = 0; f < 4; ++f) {
    int grow = m0 + ((f >> 1) << 7) + (wm << 5) + ((f & 1) << 4) + q4;
#pragma unroll
    for (int c = 0; c < 4; ++c) {
      int gcol = n0 + ((c >> 1) << 6) + (wn << 5) + ((c & 1) << 4) + r15;
      float bb = bias[gcol];
#pragma unroll
      for (int rr = 0; rr < 4; ++rr) {
        size_t o = (size_t)(grow + rr) * 512 + gcol;
        float v = acc[f][c][rr] + bb;
        if constexpr (EPI == 2) v += bf2f(addbf[o]);
        out[o] = cvt_bf16(v);
      }
    }
  }
}

// ---------------- g2: unified 128x128 BK=64 GEMM (ctx / gram / wfuse) ----------------
template <int EPI, int NKT>
__global__ __launch_bounds__(512, 4) void g2(
    const unsigned short* __restrict__ a0, const unsigned short* __restrict__ a1,
    const unsigned short* __restrict__ a2, int ald, size_t az,
    const unsigned short* __restrict__ b0, const unsigned short* __restrict__ b1,
    const unsigned short* __restrict__ b2, int bld, size_t bz,
    const float* __restrict__ bias, const unsigned short* __restrict__ addbf,
    const float* __restrict__ dden, unsigned short* __restrict__ out, int old_, size_t oz) {
  __shared__ char SA[32768], SB[32768];
  const int tid = threadIdx.x;
  const int lane = tid & 63, wave = tid >> 6;
  const int r15 = lane & 15;
  const int sq = ((lane >> 4) ^ ((r15 >> 1) & 3)) << 4;
  const int waveM = (wave >> 2) << 6;
  const int waveN = (wave & 3) << 5;
  const int m0 = blockIdx.x * 128, n0 = blockIdx.y * 128;
  const int z = blockIdx.z;
  const unsigned short* A0 = a0 + (size_t)z * az;
  const unsigned short* A1 = a1 + (size_t)z * az;
  const unsigned short* A2 = a2 + (size_t)z * az;
  const unsigned short* B0 = b0 + (size_t)z * bz;
  const unsigned short* B1 = b1 + (size_t)z * bz;
  const unsigned short* B2 = b2 + (size_t)z * bz;
  const int strow = tid >> 2;
  const int stcol = ((tid & 3) ^ ((tid >> 3) & 3)) << 3;
  const int lofs = tid * 16;
  f32x4 acc[4][2] = {};

#define STAGE_T(KT, SL)                                                                 \
  do {                                                                                  \
    const unsigned short* ab_ = seg_sel(A0, A1, A2, (KT) >> 3) +                        \
                                (size_t)(m0 + strow) * ald + (((KT)&7) << 6) + stcol;   \
    const unsigned short* bb_ = seg_sel(B0, B1, B2, (KT) >> 3) +                        \
                                (size_t)(n0 + strow) * bld + (((KT)&7) << 6) + stcol;   \
    GL16(ab_, SA + (SL)*16384 + lofs);                                                  \
    GL16(ab_ + 32, SA + (SL)*16384 + 8192 + lofs);                                      \
    GL16(bb_, SB + (SL)*16384 + lofs);                                                  \
    GL16(bb_ + 32, SB + (SL)*16384 + 8192 + lofs);                                      \
  } while (0)

  STAGE_T(0, 0);
  for (int kt = 0; kt < NKT; ++kt) {
    const int sl = kt & 1;
    if (kt + 1 < NKT) {
      STAGE_T(kt + 1, sl ^ 1);
      wait_vm_bar<4>();
    } else {
      wait_vm_bar<0>();
    }
    const char* abase = SA + sl * 16384 + (waveM + r15) * 64 + sq;
    const char* bbase = SB + sl * 16384 + (waveN + r15) * 64 + sq;
    __builtin_amdgcn_s_setprio(1);
#pragma unroll
    for (int kp = 0; kp < 2; ++kp) {
      bf16x8 af[4], bfv[2];
#pragma unroll
      for (int i = 0; i < 4; ++i) af[i] = *(const bf16x8*)(abase + kp * 8192 + i * 1024);
#pragma unroll
      for (int j = 0; j < 2; ++j) bfv[j] = *(const bf16x8*)(bbase + kp * 8192 + j * 1024);
#pragma unroll
      for (int i = 0; i < 4; ++i)
#pragma unroll
        for (int j = 0; j < 2; ++j)
          acc[i][j] = __builtin_amdgcn_mfma_f32_16x16x32_bf16(af[i], bfv[j], acc[i][j], 0, 0, 0);
    }
    __builtin_amdgcn_s_setprio(0);
    tail_bar();
  }
#undef STAGE_T

  const int q4 = (lane >> 4) << 2;
#pragma unroll
  for (int i = 0; i < 4; ++i) {
    int row = m0 + waveM + i * 16 + q4;
    if constexpr (EPI == 3) {
#pragma unroll
      for (int rr = 0; rr < 4; ++rr) {
        float inv = 1.f / dden[z + (size_t)(row + rr) * 16];
#pragma unroll
        for (int j = 0; j < 2; ++j) {
          int col = n0 + waveN + j * 16 + r15;
          out[(size_t)z * oz + (size_t)(row + rr) * old_ + col] = cvt_bf16(acc[i][j][rr] * inv);
        }
      }
    } else {
#pragma unroll
      for (int j = 0; j < 2; ++j) {
        int col = n0 + waveN + j * 16 + r15;
        float bb = (EPI == 4) ? 0.f : bias[col];
#pragma unroll
        for (int rr = 0; rr < 4; ++rr) {
          size_t o = (size_t)z * oz + (size_t)(row + rr) * old_ + col;
          float v = acc[i][j][rr] + bb;
          if constexpr (EPI == 2) v += bf2f(addbf[o]);
          out[o] = cvt_bf16(v);
        }
      }
    }
  }
}

// ---------------- MFMA output projection ----------------
__global__ __launch_bounds__(256, 4) void k_outm(const unsigned short* __restrict__ hd,
                                                 const unsigned short* __restrict__ embd,
                                                 const unsigned short* __restrict__ wcat2,
                                                 const float* __restrict__ bcat2,
                                                 float* __restrict__ out) {
  __shared__ char SA[32768];
  __shared__ char SBo[8192];
  const int tid = threadIdx.x;
  const int lane = tid & 63, wave = tid >> 6;
  const int r15 = lane & 15;
  const int sq = ((lane >> 4) ^ ((r15 >> 1) & 3)) << 4;
  const int waveM = wave << 5;
  const int m0 = blockIdx.x * 128;
  f32x4 acc[2][2] = {};

#define OSTAGE(KT, SL)                                                                     \
  do {                                                                                     \
    const unsigned short* aseg = ((KT) < 8) ? hd : embd;                                   \
    int kc = ((KT)&7) << 6;                                                                \
    _Pragma("unroll") for (int q = 0; q < 2; ++q) {                                        \
      int unit = q * 256 + tid;                                                            \
      int row = unit >> 2, chunk = unit & 3;                                               \
      int swc = chunk ^ ((row >> 1) & 3);                                                  \
      GL16(aseg + (size_t)(m0 + row) * 512 + kc + swc * 8, SA + (SL)*16384 + unit * 16);   \
      GL16(aseg + (size_t)(m0 + row) * 512 + kc + 32 + swc * 8,                            \
           SA + (SL)*16384 + 8192 + unit * 16);                                            \
    }                                                                                      \
    {                                                                                      \
      int half = tid >> 7;                                                                 \
      int u = tid & 127;                                                                   \
      int row = u >> 2, chunk = u & 3;                                                     \
      int swc = chunk ^ ((row >> 1) & 3);                                                  \
      GL16(wcat2 + (size_t)row * 1024 + ((KT) << 6) + half * 32 + swc * 8,                 \
           SBo + (SL)*4096 + half * 2048 + u * 16);                                        \
    }                                                                                      \
  } while (0)

  OSTAGE(0, 0);
  for (int kt = 0; kt < 16; ++kt) {
    const int sl = kt & 1;
    if (kt + 1 < 16) {
      OSTAGE(kt + 1, sl ^ 1);
      wait_vm_bar<5>();
    } else {
      wait_vm_bar<0>();
    }
    const char* abase = SA + sl * 16384 + (waveM + r15) * 64 + sq;
    const char* bbase = SBo + sl * 4096 + r15 * 64 + sq;
    __builtin_amdgcn_s_setprio(1);
#pragma unroll
    for (int kp = 0; kp < 2; ++kp) {
      bf16x8 af[2], bfv[2];
#pragma unroll
      for (int i = 0; i < 2; ++i) af[i] = *(const bf16x8*)(abase + kp * 8192 + i * 1024);
#pragma unroll
      for (int j = 0; j < 2; ++j) bfv[j] = *(const bf16x8*)(bbase + kp * 2048 + j * 1024);
#pragma unroll
      for (int i = 0; i < 2; ++i)
#pragma unroll
        for (int j = 0; j < 2; ++j)
          acc[i][j] = __builtin_amdgcn_mfma_f32_16x16x32_bf16(af[i], bfv[j], acc[i][j], 0, 0, 0);
    }
    __builtin_amdgcn_s_setprio(0);
    tail_bar();
  }
#undef OSTAGE

  const int q4 = (lane >> 4) << 2;
#pragma unroll
  for (int i = 0; i < 2; ++i) {
    int row = m0 + waveM + i * 16 + q4;
#pragma unroll
    for (int j = 0; j < 2; ++j) {
      int col = j * 16 + r15;
      float bb = bcat2[col];
#pragma unroll
      for (int rr = 0; rr < 4; ++rr) out[(size_t)(row + rr) * 32 + col] = acc[i][j][rr] + bb;
    }
  }
}

// ---------------- setup kernels ----------------

__global__ __launch_bounds__(256) void emb_kernel(const int* __restrict__ labels,
                                                  const float* __restrict__ labW,
                                                  const float* __restrict__ timeW,
                                                  unsigned short* __restrict__ embd) {
  int idx = blockIdx.x * 256 + threadIdx.x;
  int dd = idx & 511;
  int m = idx >> 9;
  int t = m >> 4;
  embd[idx] = cvt_bf16(labW[labels[m] * 512 + dd] + timeW[t * 512 + dd]);
}

__global__ void k_zeropad(unsigned short* a, unsigned short* b, unsigned short* c) {
  int i = blockIdx.x * 256 + threadIdx.x;
  a[i] = 0; b[i] = 0; c[i] = 0;
}

__global__ void k_wcat(const float* __restrict__ wx, const float* __restrict__ wg,
                       unsigned short* __restrict__ wcat) {
  int idx = blockIdx.x * 256 + threadIdx.x;
  int k = idx % 1536;
  int tmp = idx / 1536;
  int orow = tmp & 1023;
  int l = tmp >> 10;
  int tap = k >> 9, c = k & 511;
  int q = orow >> 5, r = orow & 31;
  int srow = q * 16 + (r & 15);
  const float* src = (r < 16) ? wx : wg;
  float v = src[(((size_t)l * 512 + srow) * 512 + c) * 3 + tap];
  wcat[idx] = cvt_bf16(v);
}

__global__ void k_biascat(const float* __restrict__ bx, const float* __restrict__ bg,
                          float* __restrict__ bcat) {
  int idx = blockIdx.x * 256 + threadIdx.x;
  int orow = idx & 1023, l = idx >> 10;
  int q = orow >> 5, r = orow & 31;
  bcat[idx] = (r < 16) ? bx[l * 512 + q * 16 + r] : bg[l * 512 + q * 16 + (r & 15)];
}

__global__ void k_wcat2(const float* __restrict__ opw, const float* __restrict__ orw,
                        const float* __restrict__ opb, const float* __restrict__ orb,
                        unsigned short* __restrict__ wcat2, float* __restrict__ bcat2) {
  int idx = blockIdx.x * 256 + threadIdx.x;
  int v = idx >> 10, k = idx & 1023;
  float val = (k < 512) ? opw[v * 512 + k] : orw[v * 512 + k - 512];
  wcat2[idx] = cvt_bf16(val);
  if (idx < 32) bcat2[idx] = opb[idx] + orb[idx];
}

__global__ void cast_kernel(const float* __restrict__ src, unsigned short* __restrict__ dst,
                            int n) {
  int i = blockIdx.x * 256 + threadIdx.x;
  if (i < n) dst[i] = cvt_bf16(src[i]);
}

__global__ __launch_bounds__(256) void k_tr512(const float* __restrict__ w,
                                               unsigned short* __restrict__ wt) {
  __shared__ unsigned short t[64][65];
  int r0 = blockIdx.x * 64, c0 = blockIdx.y * 64;
  size_t base = (size_t)blockIdx.z * 512 * 512;
  int c = threadIdx.x & 63, rr = threadIdx.x >> 6;
#pragma unroll
  for (int i = 0; i < 16; ++i) {
    int r = rr + i * 4;
    t[r][c] = cvt_bf16(w[base + (size_t)(r0 + r) * 512 + c0 + c]);
  }
  __syncthreads();
#pragma unroll
  for (int i = 0; i < 16; ++i) {
    int r = rr + i * 4;
    wt[base + (size_t)(c0 + r) * 512 + r0 + c] = t[c][r];
  }
}

__global__ void esum_kernel(const float* __restrict__ enc, float* __restrict__ Esum) {
  int p = blockIdx.x * 256 + threadIdx.x;
  float s = 0.f;
  for (int ss = 0; ss < Sn; ++ss) s += enc[(size_t)ss * Bn * En + p];
  Esum[p] = s;
}

__global__ __launch_bounds__(256) void k_encT(const float* __restrict__ enc,
                                              unsigned short* __restrict__ encT) {
  __shared__ unsigned short t[64][66];
  int s0 = blockIdx.x * 64, e0 = blockIdx.y * 64, b = blockIdx.z;
  int c = threadIdx.x & 63, r0 = threadIdx.x >> 6;
#pragma unroll
  for (int i = 0; i < 16; ++i) {
    int r = r0 + i * 4;
    t[r][c] = cvt_bf16(enc[((size_t)(s0 + r) * Bn + b) * En + e0 + c]);
  }
  __syncthreads();
#pragma unroll
  for (int i = 0; i < 16; ++i) {
    int r = r0 + i * 4;
    encT[((size_t)b * En + e0 + r) * Sn + s0 + c] = t[c][r];
  }
}

__global__ void k_biasprep(const float* __restrict__ i2e, const float* __restrict__ res_b,
                           const float* __restrict__ in2enc_b, const float* __restrict__ lab2enc_b,
                           const float* __restrict__ e2i_b, const float* __restrict__ inres_b,
                           float* __restrict__ bd, float* __restrict__ bh) {
  int idx = blockIdx.x * 256 + threadIdx.x;
  int l = idx >> 9;
  float v = 0.f;
  const float* row = i2e + (size_t)idx * 512;
  const float* rb = res_b + l * 512;
  for (int c = 0; c < 512; ++c) v += row[c] * rb[c];
  bd[idx] = v + in2enc_b[idx] + lab2enc_b[idx];
  bh[idx] = res_b[idx] + e2i_b[idx] + inres_b[idx];
}

__global__ __launch_bounds__(256) void den_kernel(const unsigned short* __restrict__ d,
                                                  const float* __restrict__ Esum,
                                                  float* __restrict__ den) {
  int gtid = blockIdx.x * 256 + threadIdx.x;
  int row = gtid >> 6;
  int lane = threadIdx.x & 63;
  int b = row & 15;
  const unsigned short* dp = d + (size_t)row * 512 + lane * 8;
  const float* ep = Esum + b * 512 + lane * 8;
  float s = 0.f;
#pragma unroll
  for (int q = 0; q < 8; ++q) s += bf2f(dp[q]) * ep[q];
  for (int off = 32; off; off >>= 1) s += __shfl_down(s, off, 64);
  if (lane == 0) den[row] = s;
}

// ---------------- host ----------------

extern "C" void kernel_launch(void* const* d_in, const int* in_sizes, int n_in,
                              void* d_out, int out_size, void* d_ws, size_t ws_size,
                              hipStream_t stream) {
  const int* labels = (const int*)d_in[0];
  const float* enc = (const float*)d_in[1];
  const float* labW = (const float*)d_in[2];
  const float* timeW = (const float*)d_in[3];
  const float* conv_glu_w = (const float*)d_in[4];
  const float* conv_glu_b = (const float*)d_in[5];
  const float* conv_id_w = (const float*)d_in[6];
  const float* conv_id_b = (const float*)d_in[7];
  const float* res_proj_w = (const float*)d_in[8];
  const float* res_proj_b = (const float*)d_in[9];
  const float* inres_w = (const float*)d_in[10];
  const float* inres_b = (const float*)d_in[11];
  const float* in2enc_w = (const float*)d_in[12];
  const float* in2enc_b = (const float*)d_in[13];
  const float* lab2enc_w = (const float*)d_in[14];
  const float* lab2enc_b = (const float*)d_in[15];
  const float* enc2in_w = (const float*)d_in[16];
  const float* enc2in_b = (const float*)d_in[17];
  const float* out_res_w = (const float*)d_in[18];
  const float* out_res_b = (const float*)d_in[19];
  const float* out_proj_w = (const float*)d_in[20];
  const float* out_proj_b = (const float*)d_in[21];
  float* out = (float*)d_out;

  char* cur = (char*)d_ws;
  auto alloc = [&](size_t bytes) {
    char* p = cur;
    cur += (bytes + 255) & ~(size_t)255;
    return p;
  };
  const size_t BIG = (size_t)MROWS * 512;
  const size_t WN = (size_t)Ln * Cn * Cn;
  const size_t ZL = (size_t)512 * 512;
  float* den = (float*)alloc(MROWS * 4);
  float* EsumB = (float*)alloc(Bn * En * 4);
  float* bd = (float*)alloc(Ln * 512 * 4);
  float* bh = (float*)alloc(Ln * 512 * 4);
  float* bcat = (float*)alloc(Ln * 1024 * 4);
  float* bcat2 = (float*)alloc(32 * 4);
  unsigned short* embp = (unsigned short*)alloc((PADE + BIG) * 2);
  unsigned short* h0p = (unsigned short*)alloc((PADE + BIG) * 2);
  unsigned short* h1p = (unsigned short*)alloc((PADE + BIG) * 2);
  unsigned short* glubf = (unsigned short*)alloc(BIG * 2);
  unsigned short* dbf = (unsigned short*)alloc(BIG * 2);
  unsigned short* ctxbf = (unsigned short*)alloc(BIG * 2);
  unsigned short* encT = (unsigned short*)alloc((size_t)Bn * En * Sn * 2);
  unsigned short* Mbf = (unsigned short*)alloc((size_t)Bn * En * En * 2);
  unsigned short* wres = (unsigned short*)alloc(WN * 2);
  unsigned short* resT = (unsigned short*)alloc(WN * 2);
  unsigned short* wfuse = (unsigned short*)alloc(WN * 2);
  unsigned short* wcat = (unsigned short*)alloc((size_t)Ln * 1024 * 1536 * 2);
  unsigned short* wcat2 = (unsigned short*)alloc((size_t)32 * 1024 * 2);
  unsigned short* w_i2e = (unsigned short*)alloc(WN * 2);
  unsigned short* w_l2e = (unsigned short*)alloc(WN * 2);
  unsigned short* w_inr = (unsigned short*)alloc(WN * 2);
  unsigned short* w_e2i = (unsigned short*)alloc(WN * 2);

  unsigned short* embd = embp + PADE;
  unsigned short* h0d = h0p + PADE;
  unsigned short* h1d = h1p + PADE;

  emb_kernel<<<MROWS * 512 / 256, 256, 0, stream>>>(labels, labW, timeW, embd);
  k_zeropad<<<PADE / 256, 256, 0, stream>>>(embp, h0p, h1p);
  k_wcat<<<Ln * 1024 * 1536 / 256, 256, 0, stream>>>(conv_glu_w, conv_id_w, wcat);
  k_biascat<<<Ln * 1024 / 256, 256, 0, stream>>>(conv_glu_b, conv_id_b, bcat);
  k_wcat2<<<32 * 1024 / 256, 256, 0, stream>>>(out_proj_w, out_res_w, out_proj_b, out_res_b,
                                               wcat2, bcat2);
  cast_kernel<<<WN / 256, 256, 0, stream>>>(res_proj_w, wres, WN);
  cast_kernel<<<WN / 256, 256, 0, stream>>>(in2enc_w, w_i2e, WN);
  cast_kernel<<<WN / 256, 256, 0, stream>>>(lab2enc_w, w_l2e, WN);
  cast_kernel<<<WN / 256, 256, 0, stream>>>(inres_w, w_inr, WN);
  cast_kernel<<<WN / 256, 256, 0, stream>>>(enc2in_w, w_e2i, WN);
  k_tr512<<<dim3(8, 8, Ln), 256, 0, stream>>>(res_proj_w, resT);
  k_biasprep<<<Ln * 512 / 256, 256, 0, stream>>>(in2enc_w, res_proj_b, in2enc_b, lab2enc_b,
                                                 enc2in_b, inres_b, bd, bh);
  esum_kernel<<<Bn * En / 256, 256, 0, stream>>>(enc, EsumB);
  k_encT<<<dim3(Sn / 64, En / 64, Bn), 256, 0, stream>>>(enc, encT);
  g2<4, 8><<<dim3(4, 4, Bn), 512, 0, stream>>>(encT, encT, encT, Sn, ZL, encT, encT, encT, Sn,
                                               ZL, nullptr, nullptr, nullptr, Mbf, 512, ZL);
  g2<4, 8><<<dim3(4, 4, Ln), 512, 0, stream>>>(w_i2e, w_i2e, w_i2e, 512, ZL, resT, resT, resT,
                                               512, ZL, nullptr, nullptr, nullptr, wfuse, 512, ZL);

  const unsigned short* hdata = embd;
  unsigned short* hbufs[2] = {h0d, h1d};
  for (int l = 0; l < Ln; ++l) {
    const size_t wo = (size_t)l * Cn * Cn;
    const unsigned short* wc = wcat + (size_t)l * 1024 * 1536;
    // glu = (h*Wx+bx)*sigmoid(h*Wg+bg)
    g3glu<<<dim3(64, 4), 512, 0, stream>>>(hdata, wc, bcat + l * 1024, glubf);
    // d = glu@i2e + h@W' + emb@l2e + bd
    g3t<1><<<dim3(64, 4), 512, 0, stream>>>(glubf, hdata, embd, w_i2e + wo, wfuse + wo,
                                            w_l2e + wo, bd + l * 512, nullptr, dbf);
    den_kernel<<<MROWS / 4, 256, 0, stream>>>(dbf, EsumB, den);
    // ctx = (d @ M[b]) / den
    g2<3, 8><<<dim3(8, 4, Bn), 512, 0, stream>>>(dbf, dbf, dbf, 8192, 512, Mbf, Mbf, Mbf, 512,
                                                 ZL, nullptr, nullptr, den, ctxbf, 8192, 512);
    // h_out = h@res^T + ctx@e2i + emb@inres + bh + glu
    g3t<2><<<dim3(64, 4), 512, 0, stream>>>(hdata, ctxbf, embd, wres + wo, w_e2i + wo,
                                            w_inr + wo, bh + l * 512, glubf, hbufs[l & 1]);
    hdata = hbufs[l & 1];
  }

  k_outm<<<MROWS / 128, 256, 0, stream>>>(hdata, embd, wcat2, bcat2, out);
}